// Round 1
// baseline (358.589 us; speedup 1.0000x reference)
//
#include <hip/hip_runtime.h>
#include <hip/hip_bf16.h>

typedef __attribute__((ext_vector_type(8))) short short8;
typedef __attribute__((ext_vector_type(8))) unsigned short ushort8;
typedef __attribute__((ext_vector_type(4))) float floatx4;

#define DEV static __device__ __forceinline__

DEV unsigned short f2bf(float f) {
  unsigned int u = __builtin_bit_cast(unsigned int, f);
  u += 0x7fff + ((u >> 16) & 1);   // round-to-nearest-even (no NaN inputs here)
  return (unsigned short)(u >> 16);
}

DEV void gload_lds16(const void* g, void* l) {
  __builtin_amdgcn_global_load_lds(
      (const __attribute__((address_space(1))) unsigned int*)g,
      (__attribute__((address_space(3))) unsigned int*)l, 16, 0, 0);
}

// ---------------- f32 -> bf16 converter (weights) ----------------
__global__ __launch_bounds__(256) void cvt_kernel(const float* __restrict__ in,
                                                  unsigned short* __restrict__ out,
                                                  int n4) {
  int i = blockIdx.x * 256 + threadIdx.x;
  if (i >= n4) return;
  float4 v = reinterpret_cast<const float4*>(in)[i];
  ushort4 o;
  o.x = f2bf(v.x); o.y = f2bf(v.y); o.z = f2bf(v.z); o.w = f2bf(v.w);
  reinterpret_cast<ushort4*>(out)[i] = o;
}

// ---------------- LayerNorm: f32 [rows][1024] -> bf16 ----------------
__global__ __launch_bounds__(256) void ln_kernel(const float* __restrict__ x,
                                                 const float* __restrict__ w,
                                                 const float* __restrict__ b,
                                                 unsigned short* __restrict__ out) {
  const int row = blockIdx.x;
  const float* xr = x + (size_t)row * 1024;
  float4 v = reinterpret_cast<const float4*>(xr)[threadIdx.x];
  float s  = v.x + v.y + v.z + v.w;
  float ss = v.x*v.x + v.y*v.y + v.z*v.z + v.w*v.w;
  #pragma unroll
  for (int off = 1; off < 64; off <<= 1) {
    s  += __shfl_xor(s, off);
    ss += __shfl_xor(ss, off);
  }
  __shared__ float red[8];
  const int wid = threadIdx.x >> 6, lane = threadIdx.x & 63;
  if (lane == 0) { red[wid] = s; red[4 + wid] = ss; }
  __syncthreads();
  s  = red[0] + red[1] + red[2] + red[3];
  ss = red[4] + red[5] + red[6] + red[7];
  const float mu  = s * (1.0f / 1024.0f);
  const float var = ss * (1.0f / 1024.0f) - mu * mu;
  const float rstd = rsqrtf(var + 1e-5f);
  float4 wv = reinterpret_cast<const float4*>(w)[threadIdx.x];
  float4 bv = reinterpret_cast<const float4*>(b)[threadIdx.x];
  ushort4 o;
  o.x = f2bf((v.x - mu) * rstd * wv.x + bv.x);
  o.y = f2bf((v.y - mu) * rstd * wv.y + bv.y);
  o.z = f2bf((v.z - mu) * rstd * wv.z + bv.z);
  o.w = f2bf((v.w - mu) * rstd * wv.w + bv.w);
  reinterpret_cast<ushort4*>(out)[(size_t)row * 256 + threadIdx.x] = o;
}

// ---------------- GEMM: C[M,N] = A[M,K](bf16) * B[N,K]^T(bf16) ----------------
// EPI 0: store bf16. EPI 1: +bias, exact GELU, store bf16. EPI 2: +bias+resid, store f32.
template<int EPI>
__global__ __launch_bounds__(256) void gemm_bt(const unsigned short* __restrict__ A,
                                               const unsigned short* __restrict__ Bw,
                                               unsigned short* __restrict__ outb,
                                               float* __restrict__ outf,
                                               const float* __restrict__ bias,
                                               const float* __restrict__ resid,
                                               int K, int N) {
  __shared__ unsigned short As[128 * 32];
  __shared__ unsigned short Bs[128 * 32];
  const int tid = threadIdx.x;
  const int lane = tid & 63;
  const int wid = tid >> 6;
  const int wrow = (wid >> 1) * 64, wcol = (wid & 1) * 64;
  const int brow = blockIdx.y * 128, bcol = blockIdx.x * 128;

  const int srow = tid >> 2, sslot = tid & 3;   // staging: 4x16B per 64B row (BK=32 bf16)
  const unsigned short* Ag0 = A  + (size_t)(brow + srow)      * K + sslot * 8;
  const unsigned short* Ag1 = A  + (size_t)(brow + 64 + srow) * K + sslot * 8;
  const unsigned short* Bg0 = Bw + (size_t)(bcol + srow)      * K + sslot * 8;
  const unsigned short* Bg1 = Bw + (size_t)(bcol + 64 + srow) * K + sslot * 8;
  unsigned short* Al0 = As + tid * 8;
  unsigned short* Al1 = As + (256 + tid) * 8;
  unsigned short* Bl0 = Bs + tid * 8;
  unsigned short* Bl1 = Bs + (256 + tid) * 8;

  floatx4 acc[4][4];
  #pragma unroll
  for (int i = 0; i < 4; i++)
    #pragma unroll
    for (int j = 0; j < 4; j++) acc[i][j] = (floatx4){0.f, 0.f, 0.f, 0.f};

  const int fr = lane & 15, fk = (lane >> 4) * 8;

  for (int kt = 0; kt < K; kt += 32) {
    gload_lds16(Ag0 + kt, Al0);
    gload_lds16(Ag1 + kt, Al1);
    gload_lds16(Bg0 + kt, Bl0);
    gload_lds16(Bg1 + kt, Bl1);
    __syncthreads();
    short8 af[4], bf[4];
    #pragma unroll
    for (int i = 0; i < 4; i++)
      af[i] = *reinterpret_cast<const short8*>(As + (wrow + i * 16 + fr) * 32 + fk);
    #pragma unroll
    for (int j = 0; j < 4; j++)
      bf[j] = *reinterpret_cast<const short8*>(Bs + (wcol + j * 16 + fr) * 32 + fk);
    #pragma unroll
    for (int i = 0; i < 4; i++)
      #pragma unroll
      for (int j = 0; j < 4; j++)
        acc[i][j] = __builtin_amdgcn_mfma_f32_16x16x32_bf16(af[i], bf[j], acc[i][j], 0, 0, 0);
    __syncthreads();
  }

  const int erow = brow + wrow + ((lane >> 4) << 2);
  const int ecol = bcol + wcol + (lane & 15);
  #pragma unroll
  for (int i = 0; i < 4; i++) {
    #pragma unroll
    for (int j = 0; j < 4; j++) {
      const int col = ecol + j * 16;
      #pragma unroll
      for (int r = 0; r < 4; r++) {
        const size_t idx = (size_t)(erow + i * 16 + r) * N + col;
        float v = acc[i][j][r];
        if (EPI == 0) {
          outb[idx] = f2bf(v);
        } else if (EPI == 1) {
          v += bias[col];
          v = 0.5f * v * (1.0f + erff(v * 0.70710678118654752f));
          outb[idx] = f2bf(v);
        } else {
          v += bias[col] + resid[idx];
          outf[idx] = v;
        }
      }
    }
  }
}

// ---------------- Flash attention ----------------
// qkv: bf16 [B*N][3072], layout col = c*1024 + h*64 + s (c=0:q,1:k,2:v)
// y:   bf16 [B*N][1024]
__global__ __launch_bounds__(256) void attn_kernel(const unsigned short* __restrict__ qkv,
                                                   unsigned short* __restrict__ y) {
  __shared__ unsigned short Ks[64 * 64];
  __shared__ unsigned short VTs[64 * 64];
  __shared__ unsigned short Ps[4][16 * 64];

  const int tid = threadIdx.x;
  const int lane = tid & 63;
  const int w = tid >> 6;
  const int qt = blockIdx.x;          // 0..15 q-tile
  const int bh = blockIdx.y;          // 0..63
  const int b = bh >> 4, h = bh & 15;
  const int fr = lane & 15, fk = (lane >> 4) * 8;
  const size_t RS = 3072;

  const unsigned short* base = qkv + (size_t)b * 1024 * RS + h * 64;

  // Q fragments (held for whole kernel)
  short8 aq[2];
  {
    const unsigned short* qrow = base + (size_t)(qt * 64 + w * 16 + fr) * RS;
    aq[0] = *reinterpret_cast<const short8*>(qrow + fk);
    aq[1] = *reinterpret_cast<const short8*>(qrow + 32 + fk);
  }

  float m_run[4], l_run[4];
  floatx4 accy[4];
  #pragma unroll
  for (int r = 0; r < 4; r++) { m_run[r] = -1e30f; l_run[r] = 0.f; }
  #pragma unroll
  for (int d = 0; d < 4; d++) accy[d] = (floatx4){0.f, 0.f, 0.f, 0.f};

  const int krow0 = tid >> 3, kslot = tid & 7;  // 64-col rows: 8x16B slots
  const unsigned short* kg0 = base + 1024 + (size_t)krow0 * RS + kslot * 8;
  const unsigned short* kg1 = base + 1024 + (size_t)(krow0 + 32) * RS + kslot * 8;
  const unsigned short* vg0 = base + 2048 + (size_t)krow0 * RS + kslot * 8;
  const unsigned short* vg1 = base + 2048 + (size_t)(krow0 + 32) * RS + kslot * 8;
  unsigned short* kl0 = Ks + tid * 8;
  unsigned short* kl1 = Ks + (256 + tid) * 8;

  for (int kt = 0; kt < 16; ++kt) {
    const size_t koff = (size_t)kt * 64 * RS;
    gload_lds16(kg0 + koff, kl0);
    gload_lds16(kg1 + koff, kl1);
    ushort8 v0 = *reinterpret_cast<const ushort8*>(vg0 + koff);
    ushort8 v1 = *reinterpret_cast<const ushort8*>(vg1 + koff);
    #pragma unroll
    for (int jj = 0; jj < 8; jj++) {
      VTs[(kslot * 8 + jj) * 64 + krow0]      = v0[jj];
      VTs[(kslot * 8 + jj) * 64 + krow0 + 32] = v1[jj];
    }
    __syncthreads();

    // S = scale * Q K^T for this wave's 16 q-rows x 64 kv-cols
    floatx4 sfr[4];
    #pragma unroll
    for (int f = 0; f < 4; ++f) {
      floatx4 s = (floatx4){0.f, 0.f, 0.f, 0.f};
      short8 kb0 = *reinterpret_cast<const short8*>(Ks + (f * 16 + fr) * 64 + fk);
      short8 kb1 = *reinterpret_cast<const short8*>(Ks + (f * 16 + fr) * 64 + 32 + fk);
      s = __builtin_amdgcn_mfma_f32_16x16x32_bf16(aq[0], kb0, s, 0, 0, 0);
      s = __builtin_amdgcn_mfma_f32_16x16x32_bf16(aq[1], kb1, s, 0, 0, 0);
      sfr[f] = s * 0.125f;
    }

    // online softmax (rows live on 16-lane groups)
    #pragma unroll
    for (int r = 0; r < 4; r++) {
      float mv = fmaxf(fmaxf(sfr[0][r], sfr[1][r]), fmaxf(sfr[2][r], sfr[3][r]));
      #pragma unroll
      for (int m = 1; m < 16; m <<= 1) mv = fmaxf(mv, __shfl_xor(mv, m));
      const float mn = fmaxf(m_run[r], mv);
      const float alpha = __expf(m_run[r] - mn);
      m_run[r] = mn;
      float ps = 0.f;
      #pragma unroll
      for (int f = 0; f < 4; f++) {
        float p = __expf(sfr[f][r] - mn);
        ps += p;
        Ps[w][((lane >> 4) * 4 + r) * 64 + f * 16 + fr] = f2bf(p);
      }
      #pragma unroll
      for (int m = 1; m < 16; m <<= 1) ps += __shfl_xor(ps, m);
      l_run[r] = l_run[r] * alpha + ps;
      #pragma unroll
      for (int d = 0; d < 4; d++) accy[d][r] *= alpha;
    }
    __syncthreads();

    // Y += P V
    #pragma unroll
    for (int ks = 0; ks < 2; ++ks) {
      short8 ap = *reinterpret_cast<const short8*>(&Ps[w][fr * 64 + ks * 32 + fk]);
      #pragma unroll
      for (int d = 0; d < 4; ++d) {
        short8 vb = *reinterpret_cast<const short8*>(VTs + (d * 16 + fr) * 64 + ks * 32 + fk);
        accy[d] = __builtin_amdgcn_mfma_f32_16x16x32_bf16(ap, vb, accy[d], 0, 0, 0);
      }
    }
    __syncthreads();
  }

  // write y (bf16) into [B*N][1024] at col h*64
  #pragma unroll
  for (int r = 0; r < 4; r++) {
    const float inv = 1.0f / l_run[r];
    const size_t grow =
        (size_t)(b * 1024 + qt * 64 + w * 16 + (lane >> 4) * 4 + r) * 1024 + h * 64;
    #pragma unroll
    for (int d = 0; d < 4; ++d)
      y[grow + d * 16 + fr] = f2bf(accy[d][r] * inv);
  }
}

// ---------------- launcher ----------------
extern "C" void kernel_launch(void* const* d_in, const int* in_sizes, int n_in,
                              void* d_out, int out_size, void* d_ws, size_t ws_size,
                              hipStream_t stream) {
  const float* x      = (const float*)d_in[0];
  const float* qkv_w  = (const float*)d_in[1];
  const float* proj_w = (const float*)d_in[2];
  const float* proj_b = (const float*)d_in[3];
  const float* ln1_w  = (const float*)d_in[4];
  const float* ln1_b  = (const float*)d_in[5];
  const float* fc1_w  = (const float*)d_in[6];
  const float* fc1_b  = (const float*)d_in[7];
  const float* fc2_w  = (const float*)d_in[8];
  const float* fc2_b  = (const float*)d_in[9];
  const float* ln2_w  = (const float*)d_in[10];
  const float* ln2_b  = (const float*)d_in[11];
  float* out = (float*)d_out;

  char* ws = (char*)d_ws;
  unsigned short* qkvw16  = (unsigned short*)(ws + 0);          //  6.0 MB
  unsigned short* projw16 = (unsigned short*)(ws + 6291456);    //  2.0 MB
  unsigned short* fc1w16  = (unsigned short*)(ws + 8388608);    //  8.0 MB
  unsigned short* fc2w16  = (unsigned short*)(ws + 16777216);   //  8.0 MB
  float*          x1      = (float*)(ws + 25165824);            // 16.0 MB f32
  unsigned short* xn      = (unsigned short*)(ws + 41943040);   //  8.0 MB (xn1 / y / xn2)
  unsigned short* big     = (unsigned short*)(ws + 50331648);   // 32.0 MB (qkvout / h)

  // weights -> bf16
  cvt_kernel<<<3072, 256, 0, stream>>>(qkv_w,  qkvw16, 786432);
  cvt_kernel<<<1024, 256, 0, stream>>>(proj_w, projw16, 262144);
  cvt_kernel<<<4096, 256, 0, stream>>>(fc1_w,  fc1w16, 1048576);
  cvt_kernel<<<4096, 256, 0, stream>>>(fc2_w,  fc2w16, 1048576);

  // LN1: x -> xn (bf16)
  ln_kernel<<<4096, 256, 0, stream>>>(x, ln1_w, ln1_b, xn);
  // qkv = xn * qkv_w^T  -> big (bf16 [4096][3072])
  gemm_bt<0><<<dim3(24, 32), 256, 0, stream>>>(xn, qkvw16, big, nullptr, nullptr, nullptr, 1024, 3072);
  // attention: big -> xn (y, bf16 [4096][1024])
  attn_kernel<<<dim3(16, 64), 256, 0, stream>>>(big, xn);
  // x1 = y * proj_w^T + proj_b + x  (f32)
  gemm_bt<2><<<dim3(8, 32), 256, 0, stream>>>(xn, projw16, nullptr, x1, proj_b, x, 1024, 1024);
  // LN2: x1 -> xn (bf16)
  ln_kernel<<<4096, 256, 0, stream>>>(x1, ln2_w, ln2_b, xn);
  // h = gelu(xn * fc1_w^T + fc1_b) -> big (bf16 [4096][4096])
  gemm_bt<1><<<dim3(32, 32), 256, 0, stream>>>(xn, fc1w16, big, nullptr, fc1_b, nullptr, 1024, 4096);
  // out = h * fc2_w^T + fc2_b + x1  (f32)
  gemm_bt<2><<<dim3(8, 32), 256, 0, stream>>>(big, fc2w16, nullptr, out, fc2_b, x1, 4096, 1024);
}

// Round 2
// 317.022 us; speedup vs baseline: 1.1311x; 1.1311x over previous
//
#include <hip/hip_runtime.h>
#include <hip/hip_bf16.h>

typedef __attribute__((ext_vector_type(8))) short short8;
typedef __attribute__((ext_vector_type(8))) unsigned short ushort8;
typedef __attribute__((ext_vector_type(4))) float floatx4;

#define DEV static __device__ __forceinline__

DEV unsigned short f2bf(float f) {
  unsigned int u = __builtin_bit_cast(unsigned int, f);
  u += 0x7fff + ((u >> 16) & 1);   // round-to-nearest-even (no NaN inputs here)
  return (unsigned short)(u >> 16);
}

DEV void gload_lds16(const void* g, void* l) {
  __builtin_amdgcn_global_load_lds(
      (const __attribute__((address_space(1))) unsigned int*)g,
      (__attribute__((address_space(3))) unsigned int*)l, 16, 0, 0);
}

// ---------------- f32 -> bf16 converter (weights) ----------------
__global__ __launch_bounds__(256) void cvt_kernel(const float* __restrict__ in,
                                                  unsigned short* __restrict__ out,
                                                  int n4) {
  int i = blockIdx.x * 256 + threadIdx.x;
  if (i >= n4) return;
  float4 v = reinterpret_cast<const float4*>(in)[i];
  ushort4 o;
  o.x = f2bf(v.x); o.y = f2bf(v.y); o.z = f2bf(v.z); o.w = f2bf(v.w);
  reinterpret_cast<ushort4*>(out)[i] = o;
}

// ---------------- LayerNorm: f32 [rows][1024] -> bf16 ----------------
__global__ __launch_bounds__(256) void ln_kernel(const float* __restrict__ x,
                                                 const float* __restrict__ w,
                                                 const float* __restrict__ b,
                                                 unsigned short* __restrict__ out) {
  const int row = blockIdx.x;
  const float* xr = x + (size_t)row * 1024;
  float4 v = reinterpret_cast<const float4*>(xr)[threadIdx.x];
  float s  = v.x + v.y + v.z + v.w;
  float ss = v.x*v.x + v.y*v.y + v.z*v.z + v.w*v.w;
  #pragma unroll
  for (int off = 1; off < 64; off <<= 1) {
    s  += __shfl_xor(s, off);
    ss += __shfl_xor(ss, off);
  }
  __shared__ float red[8];
  const int wid = threadIdx.x >> 6, lane = threadIdx.x & 63;
  if (lane == 0) { red[wid] = s; red[4 + wid] = ss; }
  __syncthreads();
  s  = red[0] + red[1] + red[2] + red[3];
  ss = red[4] + red[5] + red[6] + red[7];
  const float mu  = s * (1.0f / 1024.0f);
  const float var = ss * (1.0f / 1024.0f) - mu * mu;
  const float rstd = rsqrtf(var + 1e-5f);
  float4 wv = reinterpret_cast<const float4*>(w)[threadIdx.x];
  float4 bv = reinterpret_cast<const float4*>(b)[threadIdx.x];
  ushort4 o;
  o.x = f2bf((v.x - mu) * rstd * wv.x + bv.x);
  o.y = f2bf((v.y - mu) * rstd * wv.y + bv.y);
  o.z = f2bf((v.z - mu) * rstd * wv.z + bv.z);
  o.w = f2bf((v.w - mu) * rstd * wv.w + bv.w);
  reinterpret_cast<ushort4*>(out)[(size_t)row * 256 + threadIdx.x] = o;
}

// ---------------- GEMM: C[M,N] = A[M,K](bf16) * B[N,K]^T(bf16) ----------------
// EPI 0: store bf16. EPI 1: +bias, exact GELU, store bf16. EPI 2: +bias+resid, store f32.
template<int EPI>
__global__ __launch_bounds__(256) void gemm_bt(const unsigned short* __restrict__ A,
                                               const unsigned short* __restrict__ Bw,
                                               unsigned short* __restrict__ outb,
                                               float* __restrict__ outf,
                                               const float* __restrict__ bias,
                                               const float* __restrict__ resid,
                                               int K, int N) {
  __shared__ unsigned short As[128 * 32];
  __shared__ unsigned short Bs[128 * 32];
  const int tid = threadIdx.x;
  const int lane = tid & 63;
  const int wid = tid >> 6;
  const int wrow = (wid >> 1) * 64, wcol = (wid & 1) * 64;
  const int brow = blockIdx.y * 128, bcol = blockIdx.x * 128;

  const int srow = tid >> 2, sslot = tid & 3;   // staging: 4x16B per 64B row (BK=32 bf16)
  const unsigned short* Ag0 = A  + (size_t)(brow + srow)      * K + sslot * 8;
  const unsigned short* Ag1 = A  + (size_t)(brow + 64 + srow) * K + sslot * 8;
  const unsigned short* Bg0 = Bw + (size_t)(bcol + srow)      * K + sslot * 8;
  const unsigned short* Bg1 = Bw + (size_t)(bcol + 64 + srow) * K + sslot * 8;
  unsigned short* Al0 = As + tid * 8;
  unsigned short* Al1 = As + (256 + tid) * 8;
  unsigned short* Bl0 = Bs + tid * 8;
  unsigned short* Bl1 = Bs + (256 + tid) * 8;

  floatx4 acc[4][4];
  #pragma unroll
  for (int i = 0; i < 4; i++)
    #pragma unroll
    for (int j = 0; j < 4; j++) acc[i][j] = (floatx4){0.f, 0.f, 0.f, 0.f};

  const int fr = lane & 15, fk = (lane >> 4) * 8;

  for (int kt = 0; kt < K; kt += 32) {
    gload_lds16(Ag0 + kt, Al0);
    gload_lds16(Ag1 + kt, Al1);
    gload_lds16(Bg0 + kt, Bl0);
    gload_lds16(Bg1 + kt, Bl1);
    __syncthreads();
    short8 af[4], bf[4];
    #pragma unroll
    for (int i = 0; i < 4; i++)
      af[i] = *reinterpret_cast<const short8*>(As + (wrow + i * 16 + fr) * 32 + fk);
    #pragma unroll
    for (int j = 0; j < 4; j++)
      bf[j] = *reinterpret_cast<const short8*>(Bs + (wcol + j * 16 + fr) * 32 + fk);
    #pragma unroll
    for (int i = 0; i < 4; i++)
      #pragma unroll
      for (int j = 0; j < 4; j++)
        acc[i][j] = __builtin_amdgcn_mfma_f32_16x16x32_bf16(af[i], bf[j], acc[i][j], 0, 0, 0);
    __syncthreads();
  }

  const int erow = brow + wrow + ((lane >> 4) << 2);
  const int ecol = bcol + wcol + (lane & 15);
  #pragma unroll
  for (int i = 0; i < 4; i++) {
    #pragma unroll
    for (int j = 0; j < 4; j++) {
      const int col = ecol + j * 16;
      #pragma unroll
      for (int r = 0; r < 4; r++) {
        const size_t idx = (size_t)(erow + i * 16 + r) * N + col;
        float v = acc[i][j][r];
        if (EPI == 0) {
          outb[idx] = f2bf(v);
        } else if (EPI == 1) {
          v += bias[col];
          v = 0.5f * v * (1.0f + erff(v * 0.70710678118654752f));
          outb[idx] = f2bf(v);
        } else {
          v += bias[col] + resid[idx];
          outf[idx] = v;
        }
      }
    }
  }
}

// ---------------- V transpose: qkv[b*1024+n][2048+h*64+d] -> vt[(bh*64+d)*1024+n] ----------------
__global__ __launch_bounds__(256) void vtrans_kernel(const unsigned short* __restrict__ qkv,
                                                     unsigned short* __restrict__ vt) {
  __shared__ unsigned short T[64][66];   // [n_local][d], +2 pad
  const int nt = blockIdx.x, bh = blockIdx.y;
  const int b = bh >> 4, h = bh & 15;
  const unsigned short* src = qkv + (size_t)b * 1024 * 3072 + 2048 + h * 64;
  const int r = threadIdx.x >> 3, s = threadIdx.x & 7;
  ushort8 a0 = *reinterpret_cast<const ushort8*>(src + (size_t)(nt * 64 + r) * 3072 + s * 8);
  ushort8 a1 = *reinterpret_cast<const ushort8*>(src + (size_t)(nt * 64 + r + 32) * 3072 + s * 8);
  #pragma unroll
  for (int j = 0; j < 8; j++) {
    T[r][s * 8 + j]      = a0[j];
    T[r + 32][s * 8 + j] = a1[j];
  }
  __syncthreads();
  ushort8 o0, o1;
  #pragma unroll
  for (int j = 0; j < 8; j++) {
    o0[j] = T[s * 8 + j][r];
    o1[j] = T[s * 8 + j][r + 32];
  }
  unsigned short* dst = vt + (size_t)bh * 64 * 1024 + nt * 64 + s * 8;
  *reinterpret_cast<ushort8*>(dst + (size_t)r * 1024)        = o0;
  *reinterpret_cast<ushort8*>(dst + (size_t)(r + 32) * 1024) = o1;
}

// ---------------- Flash attention ----------------
// qkv: bf16 [B*N][3072] (q at col h*64, k at 1024+h*64); vt: bf16 [bh][64 d][1024 n]
// y:   bf16 [B*N][1024]
__global__ __launch_bounds__(256) void attn_kernel(const unsigned short* __restrict__ qkv,
                                                   const unsigned short* __restrict__ vt,
                                                   unsigned short* __restrict__ y) {
  __shared__ unsigned short Ks[2][64 * 64];  // [kv][d], slot-swizzled
  __shared__ unsigned short Vs[2][64 * 64];  // [d][kv], slot-swizzled
  __shared__ unsigned short Ps[4][16 * 64];  // per-wave [q][kv], swizzled

  const int tid = threadIdx.x;
  const int lane = tid & 63;
  const int w = tid >> 6;
  // XCD-aware bijective swizzle: 1024 blocks, 8 XCDs -> 16 qt of one bh stay on one XCD
  const int wg = (blockIdx.x & 7) * 128 + (blockIdx.x >> 3);
  const int bh = wg >> 4, qt = wg & 15;
  const int b = bh >> 4, h = bh & 15;
  const int fr = lane & 15, s0 = lane >> 4;
  const int fk = s0 * 8;
  const int sw = fr & 7;
  const size_t RS = 3072;

  const unsigned short* qbase = qkv + (size_t)b * 1024 * RS + h * 64;
  const unsigned short* kbase = qbase + 1024;
  const unsigned short* vbase = vt + (size_t)bh * 64 * 1024;

  // Q fragments (held for whole kernel)
  short8 aq[2];
  {
    const unsigned short* qrow = qbase + (size_t)(qt * 64 + w * 16 + fr) * RS;
    aq[0] = *reinterpret_cast<const short8*>(qrow + fk);
    aq[1] = *reinterpret_cast<const short8*>(qrow + 32 + fk);
  }

  float m_run[4], l_run[4];
  floatx4 accy[4];
  #pragma unroll
  for (int r = 0; r < 4; r++) { m_run[r] = -1e30f; l_run[r] = 0.f; }
  #pragma unroll
  for (int d = 0; d < 4; d++) accy[d] = (floatx4){0.f, 0.f, 0.f, 0.f};

  // staging geometry: row = tid>>3 (+32), 16B slot = tid&7; source slot inverse-swizzled
  const int krow0 = tid >> 3, kslot = tid & 7;
  const int gslot = (kslot ^ (krow0 & 7)) * 8;
  const unsigned short* kg0 = kbase + (size_t)krow0 * RS + gslot;
  const unsigned short* kg1 = kbase + (size_t)(krow0 + 32) * RS + gslot;
  const unsigned short* vg0 = vbase + (size_t)krow0 * 1024 + gslot;
  const unsigned short* vg1 = vbase + (size_t)(krow0 + 32) * 1024 + gslot;

  #define STAGE(t, buf)                                          \
    do {                                                         \
      const size_t ko = (size_t)(t) * 64 * RS;                   \
      const size_t vo = (size_t)(t) * 64;                        \
      gload_lds16(kg0 + ko, &Ks[buf][tid * 8]);                  \
      gload_lds16(kg1 + ko, &Ks[buf][(256 + tid) * 8]);          \
      gload_lds16(vg0 + vo, &Vs[buf][tid * 8]);                  \
      gload_lds16(vg1 + vo, &Vs[buf][(256 + tid) * 8]);          \
    } while (0)

  STAGE(0, 0);
  int cur = 0;

  for (int kt = 0; kt < 16; ++kt) {
    if (kt < 15) {
      STAGE(kt + 1, cur ^ 1);
      asm volatile("s_waitcnt vmcnt(4)" ::: "memory");
    } else {
      asm volatile("s_waitcnt vmcnt(0)" ::: "memory");
    }
    __builtin_amdgcn_s_barrier();

    const unsigned short* Kt = Ks[cur];
    const unsigned short* Vc = Vs[cur];

    // S = scale * Q K^T (16 q-rows x 64 kv)
    floatx4 sfr[4];
    #pragma unroll
    for (int f = 0; f < 4; ++f) {
      floatx4 s = (floatx4){0.f, 0.f, 0.f, 0.f};
      const unsigned short* krow = Kt + (f * 16 + fr) * 64;
      short8 kb0 = *reinterpret_cast<const short8*>(krow + (((s0)     ^ sw) << 3));
      short8 kb1 = *reinterpret_cast<const short8*>(krow + (((s0 + 4) ^ sw) << 3));
      s = __builtin_amdgcn_mfma_f32_16x16x32_bf16(aq[0], kb0, s, 0, 0, 0);
      s = __builtin_amdgcn_mfma_f32_16x16x32_bf16(aq[1], kb1, s, 0, 0, 0);
      sfr[f] = s * 0.125f;
    }

    // online softmax (rows live on 16-lane groups)
    #pragma unroll
    for (int r = 0; r < 4; r++) {
      float mv = fmaxf(fmaxf(sfr[0][r], sfr[1][r]), fmaxf(sfr[2][r], sfr[3][r]));
      #pragma unroll
      for (int m = 1; m < 16; m <<= 1) mv = fmaxf(mv, __shfl_xor(mv, m));
      const float mn = fmaxf(m_run[r], mv);
      const float alpha = __expf(m_run[r] - mn);
      m_run[r] = mn;
      const int q = s0 * 4 + r;
      const int qx = (q & 7) << 3;
      float ps = 0.f;
      #pragma unroll
      for (int f = 0; f < 4; f++) {
        float p = __expf(sfr[f][r] - mn);
        ps += p;
        Ps[w][q * 64 + ((f * 16 + fr) ^ qx)] = f2bf(p);
      }
      #pragma unroll
      for (int m = 1; m < 16; m <<= 1) ps += __shfl_xor(ps, m);
      l_run[r] = l_run[r] * alpha + ps;
      #pragma unroll
      for (int d = 0; d < 4; d++) accy[d][r] *= alpha;
    }

    // Y += P V   (A = P rows q, B = V^T rows d, contract over kv)
    #pragma unroll
    for (int ks = 0; ks < 2; ++ks) {
      const int sA = ((ks * 4 + s0) ^ sw) << 3;
      short8 ap = *reinterpret_cast<const short8*>(&Ps[w][fr * 64 + sA]);
      #pragma unroll
      for (int j = 0; j < 4; ++j) {
        short8 vb = *reinterpret_cast<const short8*>(Vc + (j * 16 + fr) * 64 + sA);
        accy[j] = __builtin_amdgcn_mfma_f32_16x16x32_bf16(ap, vb, accy[j], 0, 0, 0);
      }
    }
    __builtin_amdgcn_s_barrier();
    cur ^= 1;
  }
  #undef STAGE

  // write y (bf16) into [B*N][1024] at col h*64
  #pragma unroll
  for (int r = 0; r < 4; r++) {
    const float inv = 1.0f / l_run[r];
    const size_t grow =
        (size_t)(b * 1024 + qt * 64 + w * 16 + s0 * 4 + r) * 1024 + h * 64;
    #pragma unroll
    for (int d = 0; d < 4; ++d)
      y[grow + d * 16 + fr] = f2bf(accy[d][r] * inv);
  }
}

// ---------------- launcher ----------------
extern "C" void kernel_launch(void* const* d_in, const int* in_sizes, int n_in,
                              void* d_out, int out_size, void* d_ws, size_t ws_size,
                              hipStream_t stream) {
  const float* x      = (const float*)d_in[0];
  const float* qkv_w  = (const float*)d_in[1];
  const float* proj_w = (const float*)d_in[2];
  const float* proj_b = (const float*)d_in[3];
  const float* ln1_w  = (const float*)d_in[4];
  const float* ln1_b  = (const float*)d_in[5];
  const float* fc1_w  = (const float*)d_in[6];
  const float* fc1_b  = (const float*)d_in[7];
  const float* fc2_w  = (const float*)d_in[8];
  const float* fc2_b  = (const float*)d_in[9];
  const float* ln2_w  = (const float*)d_in[10];
  const float* ln2_b  = (const float*)d_in[11];
  float* out = (float*)d_out;

  char* ws = (char*)d_ws;
  unsigned short* qkvw16  = (unsigned short*)(ws + 0);          //  6.0 MB
  unsigned short* projw16 = (unsigned short*)(ws + 6291456);    //  2.0 MB
  unsigned short* fc1w16  = (unsigned short*)(ws + 8388608);    //  8.0 MB
  unsigned short* fc2w16  = (unsigned short*)(ws + 16777216);   //  8.0 MB
  float*          x1      = (float*)(ws + 25165824);            // 16.0 MB f32 (after attn)
  unsigned short* vt      = (unsigned short*)(ws + 25165824);   //  8.0 MB (dead before x1 written)
  unsigned short* xn      = (unsigned short*)(ws + 41943040);   //  8.0 MB (xn1 / y / xn2)
  unsigned short* big     = (unsigned short*)(ws + 50331648);   // 32.0 MB (qkvout / h)

  // weights -> bf16
  cvt_kernel<<<3072, 256, 0, stream>>>(qkv_w,  qkvw16, 786432);
  cvt_kernel<<<1024, 256, 0, stream>>>(proj_w, projw16, 262144);
  cvt_kernel<<<4096, 256, 0, stream>>>(fc1_w,  fc1w16, 1048576);
  cvt_kernel<<<4096, 256, 0, stream>>>(fc2_w,  fc2w16, 1048576);

  // LN1: x -> xn (bf16)
  ln_kernel<<<4096, 256, 0, stream>>>(x, ln1_w, ln1_b, xn);
  // qkv = xn * qkv_w^T  -> big (bf16 [4096][3072])
  gemm_bt<0><<<dim3(24, 32), 256, 0, stream>>>(xn, qkvw16, big, nullptr, nullptr, nullptr, 1024, 3072);
  // V^T per head -> vt
  vtrans_kernel<<<dim3(16, 64), 256, 0, stream>>>(big, vt);
  // attention: big + vt -> xn (y, bf16 [4096][1024])
  attn_kernel<<<1024, 256, 0, stream>>>(big, vt, xn);
  // x1 = y * proj_w^T + proj_b + x  (f32)
  gemm_bt<2><<<dim3(8, 32), 256, 0, stream>>>(xn, projw16, nullptr, x1, proj_b, x, 1024, 1024);
  // LN2: x1 -> xn (bf16)
  ln_kernel<<<4096, 256, 0, stream>>>(x1, ln2_w, ln2_b, xn);
  // h = gelu(xn * fc1_w^T + fc1_b) -> big (bf16 [4096][4096])
  gemm_bt<1><<<dim3(32, 32), 256, 0, stream>>>(xn, fc1w16, big, nullptr, fc1_b, nullptr, 1024, 4096);
  // out = h * fc2_w^T + fc2_b + x1  (f32)
  gemm_bt<2><<<dim3(8, 32), 256, 0, stream>>>(big, fc2w16, nullptr, out, fc2_b, x1, 4096, 1024);
}

// Round 3
// 290.841 us; speedup vs baseline: 1.2329x; 1.0900x over previous
//
#include <hip/hip_runtime.h>
#include <hip/hip_bf16.h>

typedef __attribute__((ext_vector_type(8))) short short8;
typedef __attribute__((ext_vector_type(8))) unsigned short ushort8;
typedef __attribute__((ext_vector_type(4))) float floatx4;

#define DEV static __device__ __forceinline__

DEV unsigned short f2bf(float f) {
  unsigned int u = __builtin_bit_cast(unsigned int, f);
  u += 0x7fff + ((u >> 16) & 1);   // round-to-nearest-even (no NaN inputs here)
  return (unsigned short)(u >> 16);
}

DEV void gload_lds16(const void* g, void* l) {
  __builtin_amdgcn_global_load_lds(
      (const __attribute__((address_space(1))) unsigned int*)g,
      (__attribute__((address_space(3))) unsigned int*)l, 16, 0, 0);
}

// ---------------- f32 -> bf16 converter (weights) ----------------
__global__ __launch_bounds__(256) void cvt_kernel(const float* __restrict__ in,
                                                  unsigned short* __restrict__ out,
                                                  int n4) {
  int i = blockIdx.x * 256 + threadIdx.x;
  if (i >= n4) return;
  float4 v = reinterpret_cast<const float4*>(in)[i];
  ushort4 o;
  o.x = f2bf(v.x); o.y = f2bf(v.y); o.z = f2bf(v.z); o.w = f2bf(v.w);
  reinterpret_cast<ushort4*>(out)[i] = o;
}

// ---------------- LayerNorm: f32 [rows][1024] -> bf16 ----------------
__global__ __launch_bounds__(256) void ln_kernel(const float* __restrict__ x,
                                                 const float* __restrict__ w,
                                                 const float* __restrict__ b,
                                                 unsigned short* __restrict__ out) {
  const int row = blockIdx.x;
  const float* xr = x + (size_t)row * 1024;
  float4 v = reinterpret_cast<const float4*>(xr)[threadIdx.x];
  float s  = v.x + v.y + v.z + v.w;
  float ss = v.x*v.x + v.y*v.y + v.z*v.z + v.w*v.w;
  #pragma unroll
  for (int off = 1; off < 64; off <<= 1) {
    s  += __shfl_xor(s, off);
    ss += __shfl_xor(ss, off);
  }
  __shared__ float red[8];
  const int wid = threadIdx.x >> 6, lane = threadIdx.x & 63;
  if (lane == 0) { red[wid] = s; red[4 + wid] = ss; }
  __syncthreads();
  s  = red[0] + red[1] + red[2] + red[3];
  ss = red[4] + red[5] + red[6] + red[7];
  const float mu  = s * (1.0f / 1024.0f);
  const float var = ss * (1.0f / 1024.0f) - mu * mu;
  const float rstd = rsqrtf(var + 1e-5f);
  float4 wv = reinterpret_cast<const float4*>(w)[threadIdx.x];
  float4 bv = reinterpret_cast<const float4*>(b)[threadIdx.x];
  ushort4 o;
  o.x = f2bf((v.x - mu) * rstd * wv.x + bv.x);
  o.y = f2bf((v.y - mu) * rstd * wv.y + bv.y);
  o.z = f2bf((v.z - mu) * rstd * wv.z + bv.z);
  o.w = f2bf((v.w - mu) * rstd * wv.w + bv.w);
  reinterpret_cast<ushort4*>(out)[(size_t)row * 256 + threadIdx.x] = o;
}

// ============ gemm256: C[M,N] = A[M,K] * B[N,K]^T, 256x256 tile, BK=64 ============
// 512 threads, 8 waves (2 M x 4 N), per-wave 128x64 out. Double-buffered 128KB LDS,
// counted vmcnt(8) pipeline, slot-XOR swizzle, 4-phase MFMA interleave + setprio.
// EPI 0: store bf16. EPI 1: +bias, tanh-GELU, store bf16.
template<int EPI>
__global__ __launch_bounds__(512, 2) void gemm256(const unsigned short* __restrict__ A,
                                                  const unsigned short* __restrict__ Bw,
                                                  unsigned short* __restrict__ outb,
                                                  const float* __restrict__ bias,
                                                  int K, int N, int NT) {
  __shared__ unsigned short As[2][256 * 64];
  __shared__ unsigned short Bs[2][256 * 64];
  const int tid = threadIdx.x, lane = tid & 63, wid = tid >> 6;
  const int wr = wid >> 2, wc = wid & 3;
  const int fr = lane & 15, s0 = lane >> 4;

  // T1: bijective XCD swizzle (m204)
  const int nwg = gridDim.x;
  const int qq = nwg >> 3, rr8 = nwg & 7, xcd = blockIdx.x & 7, lid = blockIdx.x >> 3;
  const int wg = (xcd < rr8 ? xcd * (qq + 1) : rr8 * (qq + 1) + (xcd - rr8) * qq) + lid;
  const int brow = (wg / NT) * 256, bcol = (wg % NT) * 256;

  // staging: 4 A + 4 B gload_lds16 per thread per K-tile.
  // LDS dest linear: idx = L*512+tid -> row=idx>>3, slot=idx&7.
  // Global source slot inverse-swizzled: src_slot = slot ^ (row&7) (rule 21).
  const unsigned short* ag[4];
  const unsigned short* bg[4];
  #pragma unroll
  for (int L = 0; L < 4; L++) {
    const int idx = L * 512 + tid;
    const int row = idx >> 3;
    const int ss  = ((idx & 7) ^ (row & 7)) * 8;
    ag[L] = A  + (size_t)(brow + row) * K + ss;
    bg[L] = Bw + (size_t)(bcol + row) * K + ss;
  }
  const int ldst = tid * 8;

  #define STG256(kt, buf)                                                     \
    do {                                                                      \
      const int ko = (kt) * 64;                                               \
      gload_lds16(ag[0] + ko, &As[buf][ldst]);                                \
      gload_lds16(ag[1] + ko, &As[buf][4096 + ldst]);                         \
      gload_lds16(ag[2] + ko, &As[buf][8192 + ldst]);                         \
      gload_lds16(ag[3] + ko, &As[buf][12288 + ldst]);                        \
      gload_lds16(bg[0] + ko, &Bs[buf][ldst]);                                \
      gload_lds16(bg[1] + ko, &Bs[buf][4096 + ldst]);                         \
      gload_lds16(bg[2] + ko, &Bs[buf][8192 + ldst]);                         \
      gload_lds16(bg[3] + ko, &Bs[buf][12288 + ldst]);                        \
    } while (0)

  // fragment read offsets (swizzled): elem k in row r lives at slot (k>>3)^(r&7)
  const int xs = fr & 7;
  const int aoff = (wr * 128 + fr) * 64;   // + m*1024 + sl[kk]
  const int boff = (wc * 64 + fr) * 64;    // + n*1024 + sl[kk]
  const int sl0 = ((0 + s0) ^ xs) * 8;
  const int sl1 = ((4 + s0) ^ xs) * 8;

  floatx4 acc[8][4];
  #pragma unroll
  for (int m = 0; m < 8; m++)
    #pragma unroll
    for (int n = 0; n < 4; n++) acc[m][n] = (floatx4){0.f, 0.f, 0.f, 0.f};

  const int NTK = K >> 6;
  STG256(0, 0);

  for (int kt = 0; kt < NTK; ++kt) {
    const int cur = kt & 1;
    if (kt + 1 < NTK) {
      STG256(kt + 1, cur ^ 1);
      asm volatile("s_waitcnt vmcnt(8)" ::: "memory");  // tile kt landed; kt+1 in flight
    } else {
      asm volatile("s_waitcnt vmcnt(0)" ::: "memory");
    }
    __builtin_amdgcn_s_barrier();

    const unsigned short* Ac = As[cur];
    const unsigned short* Bc = Bs[cur];
    short8 a0[4][2], a1[4][2], b0[2][2], b1[2][2];

    // ---- phase 0: read A(m0-3), B(n0-1); MFMA quadrant (m0-3, n0-1)
    #pragma unroll
    for (int m = 0; m < 4; m++) {
      a0[m][0] = *reinterpret_cast<const short8*>(Ac + aoff + m * 1024 + sl0);
      a0[m][1] = *reinterpret_cast<const short8*>(Ac + aoff + m * 1024 + sl1);
    }
    #pragma unroll
    for (int n = 0; n < 2; n++) {
      b0[n][0] = *reinterpret_cast<const short8*>(Bc + boff + n * 1024 + sl0);
      b0[n][1] = *reinterpret_cast<const short8*>(Bc + boff + n * 1024 + sl1);
    }
    __builtin_amdgcn_s_barrier();
    __builtin_amdgcn_s_setprio(1);
    #pragma unroll
    for (int m = 0; m < 4; m++)
      #pragma unroll
      for (int n = 0; n < 2; n++) {
        acc[m][n] = __builtin_amdgcn_mfma_f32_16x16x32_bf16(a0[m][0], b0[n][0], acc[m][n], 0, 0, 0);
        acc[m][n] = __builtin_amdgcn_mfma_f32_16x16x32_bf16(a0[m][1], b0[n][1], acc[m][n], 0, 0, 0);
      }
    __builtin_amdgcn_s_setprio(0);
    __builtin_amdgcn_s_barrier();

    // ---- phase 1: read B(n2-3); MFMA quadrant (m0-3, n2-3)
    #pragma unroll
    for (int n = 0; n < 2; n++) {
      b1[n][0] = *reinterpret_cast<const short8*>(Bc + boff + (n + 2) * 1024 + sl0);
      b1[n][1] = *reinterpret_cast<const short8*>(Bc + boff + (n + 2) * 1024 + sl1);
    }
    __builtin_amdgcn_s_barrier();
    __builtin_amdgcn_s_setprio(1);
    #pragma unroll
    for (int m = 0; m < 4; m++)
      #pragma unroll
      for (int n = 0; n < 2; n++) {
        acc[m][n + 2] = __builtin_amdgcn_mfma_f32_16x16x32_bf16(a0[m][0], b1[n][0], acc[m][n + 2], 0, 0, 0);
        acc[m][n + 2] = __builtin_amdgcn_mfma_f32_16x16x32_bf16(a0[m][1], b1[n][1], acc[m][n + 2], 0, 0, 0);
      }
    __builtin_amdgcn_s_setprio(0);
    __builtin_amdgcn_s_barrier();

    // ---- phase 2: read A(m4-7); MFMA quadrant (m4-7, n0-1)
    #pragma unroll
    for (int m = 0; m < 4; m++) {
      a1[m][0] = *reinterpret_cast<const short8*>(Ac + aoff + (m + 4) * 1024 + sl0);
      a1[m][1] = *reinterpret_cast<const short8*>(Ac + aoff + (m + 4) * 1024 + sl1);
    }
    __builtin_amdgcn_s_barrier();
    __builtin_amdgcn_s_setprio(1);
    #pragma unroll
    for (int m = 0; m < 4; m++)
      #pragma unroll
      for (int n = 0; n < 2; n++) {
        acc[m + 4][n] = __builtin_amdgcn_mfma_f32_16x16x32_bf16(a1[m][0], b0[n][0], acc[m + 4][n], 0, 0, 0);
        acc[m + 4][n] = __builtin_amdgcn_mfma_f32_16x16x32_bf16(a1[m][1], b0[n][1], acc[m + 4][n], 0, 0, 0);
      }
    __builtin_amdgcn_s_setprio(0);
    __builtin_amdgcn_s_barrier();

    // ---- phase 3: MFMA quadrant (m4-7, n2-3); no reads
    __builtin_amdgcn_s_setprio(1);
    #pragma unroll
    for (int m = 0; m < 4; m++)
      #pragma unroll
      for (int n = 0; n < 2; n++) {
        acc[m + 4][n + 2] = __builtin_amdgcn_mfma_f32_16x16x32_bf16(a1[m][0], b1[n][0], acc[m + 4][n + 2], 0, 0, 0);
        acc[m + 4][n + 2] = __builtin_amdgcn_mfma_f32_16x16x32_bf16(a1[m][1], b1[n][1], acc[m + 4][n + 2], 0, 0, 0);
      }
    __builtin_amdgcn_s_setprio(0);
    __builtin_amdgcn_s_barrier();   // all reads of 'cur' done before next tile stages into it
  }
  #undef STG256

  // epilogue
  #pragma unroll
  for (int m = 0; m < 8; m++) {
    #pragma unroll
    for (int n = 0; n < 4; n++) {
      const int col = bcol + wc * 64 + n * 16 + fr;
      #pragma unroll
      for (int r = 0; r < 4; r++) {
        const size_t idx = (size_t)(brow + wr * 128 + m * 16 + s0 * 4 + r) * N + col;
        float v = acc[m][n][r];
        if (EPI == 1) {
          v += bias[col];
          const float u = v * 0.7978845608f * (1.0f + 0.044715f * v * v);
          const float e = __expf(2.0f * u);
          v = v * (e / (e + 1.0f));   // x * sigmoid(2u) == 0.5x(1+tanh u)
        }
        outb[idx] = f2bf(v);
      }
    }
  }
}

// ============ gemm128: 128x128 tile, BK=32, dbuf + counted vmcnt + T1/T2 ============
// EPI 2 only in practice: +bias +resid, store f32.
template<int EPI>
__global__ __launch_bounds__(256) void gemm128(const unsigned short* __restrict__ A,
                                               const unsigned short* __restrict__ Bw,
                                               unsigned short* __restrict__ outb,
                                               float* __restrict__ outf,
                                               const float* __restrict__ bias,
                                               const float* __restrict__ resid,
                                               int K, int N, int NT) {
  __shared__ unsigned short As[2][128 * 32];
  __shared__ unsigned short Bs[2][128 * 32];
  const int tid = threadIdx.x, lane = tid & 63, wid = tid >> 6;
  const int wrow = (wid >> 1) * 64, wcol = (wid & 1) * 64;
  const int fr = lane & 15, s0 = lane >> 4;

  // T1 bijective XCD swizzle
  const int nwg = gridDim.x;
  const int qq = nwg >> 3, rr8 = nwg & 7, xcd = blockIdx.x & 7, lid = blockIdx.x >> 3;
  const int wg = (xcd < rr8 ? xcd * (qq + 1) : rr8 * (qq + 1) + (xcd - rr8) * qq) + lid;
  const int brow = (wg / NT) * 128, bcol = (wg % NT) * 128;

  // staging: 2 A + 2 B loads/thread; idx = L*256+tid -> row=idx>>2, slot=idx&3
  const unsigned short* ag[2];
  const unsigned short* bg[2];
  #pragma unroll
  for (int L = 0; L < 2; L++) {
    const int idx = L * 256 + tid;
    const int row = idx >> 2;
    const int ss  = ((idx & 3) ^ (row & 3)) * 8;
    ag[L] = A  + (size_t)(brow + row) * K + ss;
    bg[L] = Bw + (size_t)(bcol + row) * K + ss;
  }
  const int ldst = tid * 8;

  #define STG128(kt, buf)                                 \
    do {                                                  \
      const int ko = (kt) * 32;                           \
      gload_lds16(ag[0] + ko, &As[buf][ldst]);            \
      gload_lds16(ag[1] + ko, &As[buf][2048 + ldst]);     \
      gload_lds16(bg[0] + ko, &Bs[buf][ldst]);            \
      gload_lds16(bg[1] + ko, &Bs[buf][2048 + ldst]);     \
    } while (0)

  const int slr = (s0 ^ (fr & 3)) * 8;   // swizzled k-slot for fragment reads

  floatx4 acc[4][4];
  #pragma unroll
  for (int i = 0; i < 4; i++)
    #pragma unroll
    for (int j = 0; j < 4; j++) acc[i][j] = (floatx4){0.f, 0.f, 0.f, 0.f};

  const int NTK = K >> 5;
  STG128(0, 0);

  for (int kt = 0; kt < NTK; ++kt) {
    const int cur = kt & 1;
    if (kt + 1 < NTK) {
      STG128(kt + 1, cur ^ 1);
      asm volatile("s_waitcnt vmcnt(4)" ::: "memory");
    } else {
      asm volatile("s_waitcnt vmcnt(0)" ::: "memory");
    }
    __builtin_amdgcn_s_barrier();

    short8 af[4], bf[4];
    #pragma unroll
    for (int i = 0; i < 4; i++)
      af[i] = *reinterpret_cast<const short8*>(&As[cur][(wrow + i * 16 + fr) * 32 + slr]);
    #pragma unroll
    for (int j = 0; j < 4; j++)
      bf[j] = *reinterpret_cast<const short8*>(&Bs[cur][(wcol + j * 16 + fr) * 32 + slr]);
    __builtin_amdgcn_s_setprio(1);
    #pragma unroll
    for (int i = 0; i < 4; i++)
      #pragma unroll
      for (int j = 0; j < 4; j++)
        acc[i][j] = __builtin_amdgcn_mfma_f32_16x16x32_bf16(af[i], bf[j], acc[i][j], 0, 0, 0);
    __builtin_amdgcn_s_setprio(0);
    __builtin_amdgcn_s_barrier();
  }
  #undef STG128

  const int erow = brow + wrow + (s0 << 2);
  const int ecol = bcol + wcol + fr;
  #pragma unroll
  for (int i = 0; i < 4; i++) {
    #pragma unroll
    for (int j = 0; j < 4; j++) {
      const int col = ecol + j * 16;
      #pragma unroll
      for (int r = 0; r < 4; r++) {
        const size_t idx = (size_t)(erow + i * 16 + r) * N + col;
        float v = acc[i][j][r];
        if (EPI == 0) {
          outb[idx] = f2bf(v);
        } else if (EPI == 2) {
          v += bias[col] + resid[idx];
          outf[idx] = v;
        }
      }
    }
  }
}

// ---------------- V transpose: qkv[b*1024+n][2048+h*64+d] -> vt[(bh*64+d)*1024+n] ----------------
__global__ __launch_bounds__(256) void vtrans_kernel(const unsigned short* __restrict__ qkv,
                                                     unsigned short* __restrict__ vt) {
  __shared__ unsigned short T[64][66];   // [n_local][d], +2 pad
  const int nt = blockIdx.x, bh = blockIdx.y;
  const int b = bh >> 4, h = bh & 15;
  const unsigned short* src = qkv + (size_t)b * 1024 * 3072 + 2048 + h * 64;
  const int r = threadIdx.x >> 3, s = threadIdx.x & 7;
  ushort8 a0 = *reinterpret_cast<const ushort8*>(src + (size_t)(nt * 64 + r) * 3072 + s * 8);
  ushort8 a1 = *reinterpret_cast<const ushort8*>(src + (size_t)(nt * 64 + r + 32) * 3072 + s * 8);
  #pragma unroll
  for (int j = 0; j < 8; j++) {
    T[r][s * 8 + j]      = a0[j];
    T[r + 32][s * 8 + j] = a1[j];
  }
  __syncthreads();
  ushort8 o0, o1;
  #pragma unroll
  for (int j = 0; j < 8; j++) {
    o0[j] = T[s * 8 + j][r];
    o1[j] = T[s * 8 + j][r + 32];
  }
  unsigned short* dst = vt + (size_t)bh * 64 * 1024 + nt * 64 + s * 8;
  *reinterpret_cast<ushort8*>(dst + (size_t)r * 1024)        = o0;
  *reinterpret_cast<ushort8*>(dst + (size_t)(r + 32) * 1024) = o1;
}

// ---------------- Flash attention ----------------
// qkv: bf16 [B*N][3072] (q at col h*64, k at 1024+h*64); vt: bf16 [bh][64 d][1024 n]
// y:   bf16 [B*N][1024]
__global__ __launch_bounds__(256) void attn_kernel(const unsigned short* __restrict__ qkv,
                                                   const unsigned short* __restrict__ vt,
                                                   unsigned short* __restrict__ y) {
  __shared__ unsigned short Ks[2][64 * 64];  // [kv][d], slot-swizzled
  __shared__ unsigned short Vs[2][64 * 64];  // [d][kv], slot-swizzled
  __shared__ unsigned short Ps[4][16 * 64];  // per-wave [q][kv], swizzled

  const int tid = threadIdx.x;
  const int lane = tid & 63;
  const int w = tid >> 6;
  // XCD-aware bijective swizzle: 1024 blocks, 8 XCDs -> 16 qt of one bh stay on one XCD
  const int wg = (blockIdx.x & 7) * 128 + (blockIdx.x >> 3);
  const int bh = wg >> 4, qt = wg & 15;
  const int b = bh >> 4, h = bh & 15;
  const int fr = lane & 15, s0 = lane >> 4;
  const int fk = s0 * 8;
  const int sw = fr & 7;
  const size_t RS = 3072;

  const unsigned short* qbase = qkv + (size_t)b * 1024 * RS + h * 64;
  const unsigned short* kbase = qbase + 1024;
  const unsigned short* vbase = vt + (size_t)bh * 64 * 1024;

  // Q fragments (held for whole kernel)
  short8 aq[2];
  {
    const unsigned short* qrow = qbase + (size_t)(qt * 64 + w * 16 + fr) * RS;
    aq[0] = *reinterpret_cast<const short8*>(qrow + fk);
    aq[1] = *reinterpret_cast<const short8*>(qrow + 32 + fk);
  }

  float m_run[4], l_run[4];
  floatx4 accy[4];
  #pragma unroll
  for (int r = 0; r < 4; r++) { m_run[r] = -1e30f; l_run[r] = 0.f; }
  #pragma unroll
  for (int d = 0; d < 4; d++) accy[d] = (floatx4){0.f, 0.f, 0.f, 0.f};

  // staging geometry: row = tid>>3 (+32), 16B slot = tid&7; source slot inverse-swizzled
  const int krow0 = tid >> 3, kslot = tid & 7;
  const int gslot = (kslot ^ (krow0 & 7)) * 8;
  const unsigned short* kg0 = kbase + (size_t)krow0 * RS + gslot;
  const unsigned short* kg1 = kbase + (size_t)(krow0 + 32) * RS + gslot;
  const unsigned short* vg0 = vbase + (size_t)krow0 * 1024 + gslot;
  const unsigned short* vg1 = vbase + (size_t)(krow0 + 32) * 1024 + gslot;

  #define STAGE(t, buf)                                          \
    do {                                                         \
      const size_t ko = (size_t)(t) * 64 * RS;                   \
      const size_t vo = (size_t)(t) * 64;                        \
      gload_lds16(kg0 + ko, &Ks[buf][tid * 8]);                  \
      gload_lds16(kg1 + ko, &Ks[buf][(256 + tid) * 8]);          \
      gload_lds16(vg0 + vo, &Vs[buf][tid * 8]);                  \
      gload_lds16(vg1 + vo, &Vs[buf][(256 + tid) * 8]);          \
    } while (0)

  STAGE(0, 0);
  int cur = 0;

  for (int kt = 0; kt < 16; ++kt) {
    if (kt < 15) {
      STAGE(kt + 1, cur ^ 1);
      asm volatile("s_waitcnt vmcnt(4)" ::: "memory");
    } else {
      asm volatile("s_waitcnt vmcnt(0)" ::: "memory");
    }
    __builtin_amdgcn_s_barrier();

    const unsigned short* Kt = Ks[cur];
    const unsigned short* Vc = Vs[cur];

    // S = scale * Q K^T (16 q-rows x 64 kv)
    floatx4 sfr[4];
    #pragma unroll
    for (int f = 0; f < 4; ++f) {
      floatx4 s = (floatx4){0.f, 0.f, 0.f, 0.f};
      const unsigned short* krow = Kt + (f * 16 + fr) * 64;
      short8 kb0 = *reinterpret_cast<const short8*>(krow + (((s0)     ^ sw) << 3));
      short8 kb1 = *reinterpret_cast<const short8*>(krow + (((s0 + 4) ^ sw) << 3));
      s = __builtin_amdgcn_mfma_f32_16x16x32_bf16(aq[0], kb0, s, 0, 0, 0);
      s = __builtin_amdgcn_mfma_f32_16x16x32_bf16(aq[1], kb1, s, 0, 0, 0);
      sfr[f] = s * 0.125f;
    }

    // online softmax (rows live on 16-lane groups)
    #pragma unroll
    for (int r = 0; r < 4; r++) {
      float mv = fmaxf(fmaxf(sfr[0][r], sfr[1][r]), fmaxf(sfr[2][r], sfr[3][r]));
      #pragma unroll
      for (int m = 1; m < 16; m <<= 1) mv = fmaxf(mv, __shfl_xor(mv, m));
      const float mn = fmaxf(m_run[r], mv);
      const float alpha = __expf(m_run[r] - mn);
      m_run[r] = mn;
      const int q = s0 * 4 + r;
      const int qx = (q & 7) << 3;
      float ps = 0.f;
      #pragma unroll
      for (int f = 0; f < 4; f++) {
        float p = __expf(sfr[f][r] - mn);
        ps += p;
        Ps[w][q * 64 + ((f * 16 + fr) ^ qx)] = f2bf(p);
      }
      #pragma unroll
      for (int m = 1; m < 16; m <<= 1) ps += __shfl_xor(ps, m);
      l_run[r] = l_run[r] * alpha + ps;
      #pragma unroll
      for (int d = 0; d < 4; d++) accy[d][r] *= alpha;
    }

    // Y += P V   (A = P rows q, B = V^T rows d, contract over kv)
    #pragma unroll
    for (int ks = 0; ks < 2; ++ks) {
      const int sA = ((ks * 4 + s0) ^ sw) << 3;
      short8 ap = *reinterpret_cast<const short8*>(&Ps[w][fr * 64 + sA]);
      #pragma unroll
      for (int j = 0; j < 4; ++j) {
        short8 vb = *reinterpret_cast<const short8*>(Vc + (j * 16 + fr) * 64 + sA);
        accy[j] = __builtin_amdgcn_mfma_f32_16x16x32_bf16(ap, vb, accy[j], 0, 0, 0);
      }
    }
    __builtin_amdgcn_s_barrier();
    cur ^= 1;
  }
  #undef STAGE

  // write y (bf16) into [B*N][1024] at col h*64
  #pragma unroll
  for (int r = 0; r < 4; r++) {
    const float inv = 1.0f / l_run[r];
    const size_t grow =
        (size_t)(b * 1024 + qt * 64 + w * 16 + s0 * 4 + r) * 1024 + h * 64;
    #pragma unroll
    for (int d = 0; d < 4; ++d)
      y[grow + d * 16 + fr] = f2bf(accy[d][r] * inv);
  }
}

// ---------------- launcher ----------------
extern "C" void kernel_launch(void* const* d_in, const int* in_sizes, int n_in,
                              void* d_out, int out_size, void* d_ws, size_t ws_size,
                              hipStream_t stream) {
  const float* x      = (const float*)d_in[0];
  const float* qkv_w  = (const float*)d_in[1];
  const float* proj_w = (const float*)d_in[2];
  const float* proj_b = (const float*)d_in[3];
  const float* ln1_w  = (const float*)d_in[4];
  const float* ln1_b  = (const float*)d_in[5];
  const float* fc1_w  = (const float*)d_in[6];
  const float* fc1_b  = (const float*)d_in[7];
  const float* fc2_w  = (const float*)d_in[8];
  const float* fc2_b  = (const float*)d_in[9];
  const float* ln2_w  = (const float*)d_in[10];
  const float* ln2_b  = (const float*)d_in[11];
  float* out = (float*)d_out;

  char* ws = (char*)d_ws;
  unsigned short* qkvw16  = (unsigned short*)(ws + 0);          //  6.0 MB
  unsigned short* projw16 = (unsigned short*)(ws + 6291456);    //  2.0 MB
  unsigned short* fc1w16  = (unsigned short*)(ws + 8388608);    //  8.0 MB
  unsigned short* fc2w16  = (unsigned short*)(ws + 16777216);   //  8.0 MB
  float*          x1      = (float*)(ws + 25165824);            // 16.0 MB f32 (after attn)
  unsigned short* vt      = (unsigned short*)(ws + 25165824);   //  8.0 MB (dead before x1 written)
  unsigned short* xn      = (unsigned short*)(ws + 41943040);   //  8.0 MB (xn1 / y / xn2)
  unsigned short* big     = (unsigned short*)(ws + 50331648);   // 32.0 MB (qkvout / h)

  // weights -> bf16
  cvt_kernel<<<3072, 256, 0, stream>>>(qkv_w,  qkvw16, 786432);
  cvt_kernel<<<1024, 256, 0, stream>>>(proj_w, projw16, 262144);
  cvt_kernel<<<4096, 256, 0, stream>>>(fc1_w,  fc1w16, 1048576);
  cvt_kernel<<<4096, 256, 0, stream>>>(fc2_w,  fc2w16, 1048576);

  // LN1: x -> xn (bf16)
  ln_kernel<<<4096, 256, 0, stream>>>(x, ln1_w, ln1_b, xn);
  // qkv = xn * qkv_w^T  -> big (bf16 [4096][3072]); 16x12 = 192 blocks
  gemm256<0><<<192, 512, 0, stream>>>(xn, qkvw16, big, nullptr, 1024, 3072, 12);
  // V^T per head -> vt
  vtrans_kernel<<<dim3(16, 64), 256, 0, stream>>>(big, vt);
  // attention: big + vt -> xn (y, bf16 [4096][1024])
  attn_kernel<<<1024, 256, 0, stream>>>(big, vt, xn);
  // x1 = y * proj_w^T + proj_b + x  (f32); 32x8 = 256 blocks
  gemm128<2><<<256, 256, 0, stream>>>(xn, projw16, nullptr, x1, proj_b, x, 1024, 1024, 8);
  // LN2: x1 -> xn (bf16)
  ln_kernel<<<4096, 256, 0, stream>>>(x1, ln2_w, ln2_b, xn);
  // h = gelu(xn * fc1_w^T + fc1_b) -> big (bf16 [4096][4096]); 16x16 = 256 blocks
  gemm256<1><<<256, 512, 0, stream>>>(xn, fc1w16, big, fc1_b, 1024, 4096, 16);
  // out = h * fc2_w^T + fc2_b + x1  (f32); 32x8 = 256 blocks
  gemm128<2><<<256, 256, 0, stream>>>(big, fc2w16, nullptr, out, fc2_b, x1, 4096, 1024, 8);
}

// Round 4
// 285.791 us; speedup vs baseline: 1.2547x; 1.0177x over previous
//
#include <hip/hip_runtime.h>
#include <hip/hip_bf16.h>

typedef __attribute__((ext_vector_type(8))) short short8;
typedef __attribute__((ext_vector_type(8))) unsigned short ushort8;
typedef __attribute__((ext_vector_type(4))) float floatx4;

#define DEV static __device__ __forceinline__

DEV unsigned short f2bf(float f) {
  unsigned int u = __builtin_bit_cast(unsigned int, f);
  u += 0x7fff + ((u >> 16) & 1);   // round-to-nearest-even (no NaN inputs here)
  return (unsigned short)(u >> 16);
}

DEV void gload_lds16(const void* g, void* l) {
  __builtin_amdgcn_global_load_lds(
      (const __attribute__((address_space(1))) unsigned int*)g,
      (__attribute__((address_space(3))) unsigned int*)l, 16, 0, 0);
}

// ---------------- f32 -> bf16 converter (weights) ----------------
__global__ __launch_bounds__(256) void cvt_kernel(const float* __restrict__ in,
                                                  unsigned short* __restrict__ out,
                                                  int n4) {
  int i = blockIdx.x * 256 + threadIdx.x;
  if (i >= n4) return;
  float4 v = reinterpret_cast<const float4*>(in)[i];
  ushort4 o;
  o.x = f2bf(v.x); o.y = f2bf(v.y); o.z = f2bf(v.z); o.w = f2bf(v.w);
  reinterpret_cast<ushort4*>(out)[i] = o;
}

// ---------------- LayerNorm: f32 [rows][1024] -> bf16 ----------------
__global__ __launch_bounds__(256) void ln_kernel(const float* __restrict__ x,
                                                 const float* __restrict__ w,
                                                 const float* __restrict__ b,
                                                 unsigned short* __restrict__ out) {
  const int row = blockIdx.x;
  const float* xr = x + (size_t)row * 1024;
  float4 v = reinterpret_cast<const float4*>(xr)[threadIdx.x];
  float s  = v.x + v.y + v.z + v.w;
  float ss = v.x*v.x + v.y*v.y + v.z*v.z + v.w*v.w;
  #pragma unroll
  for (int off = 1; off < 64; off <<= 1) {
    s  += __shfl_xor(s, off);
    ss += __shfl_xor(ss, off);
  }
  __shared__ float red[8];
  const int wid = threadIdx.x >> 6, lane = threadIdx.x & 63;
  if (lane == 0) { red[wid] = s; red[4 + wid] = ss; }
  __syncthreads();
  s  = red[0] + red[1] + red[2] + red[3];
  ss = red[4] + red[5] + red[6] + red[7];
  const float mu  = s * (1.0f / 1024.0f);
  const float var = ss * (1.0f / 1024.0f) - mu * mu;
  const float rstd = rsqrtf(var + 1e-5f);
  float4 wv = reinterpret_cast<const float4*>(w)[threadIdx.x];
  float4 bv = reinterpret_cast<const float4*>(b)[threadIdx.x];
  ushort4 o;
  o.x = f2bf((v.x - mu) * rstd * wv.x + bv.x);
  o.y = f2bf((v.y - mu) * rstd * wv.y + bv.y);
  o.z = f2bf((v.z - mu) * rstd * wv.z + bv.z);
  o.w = f2bf((v.w - mu) * rstd * wv.w + bv.w);
  reinterpret_cast<ushort4*>(out)[(size_t)row * 256 + threadIdx.x] = o;
}

// ============ gemm256: C[M,N] = A[M,K] * B[N,K]^T, 256x256 tile, BK=64 ============
// 512 threads, 8 waves (2 M x 4 N), per-wave 128x64 out. Double-buffered 128KB LDS,
// counted vmcnt(8) pipeline, slot-XOR swizzle, 4-phase MFMA interleave + setprio.
// EPI 0: store bf16. EPI 1: +bias, tanh-GELU, store bf16.
template<int EPI>
__global__ __launch_bounds__(512, 2) void gemm256(const unsigned short* __restrict__ A,
                                                  const unsigned short* __restrict__ Bw,
                                                  unsigned short* __restrict__ outb,
                                                  const float* __restrict__ bias,
                                                  int K, int N, int NT) {
  __shared__ unsigned short As[2][256 * 64];
  __shared__ unsigned short Bs[2][256 * 64];
  const int tid = threadIdx.x, lane = tid & 63, wid = tid >> 6;
  const int wr = wid >> 2, wc = wid & 3;
  const int fr = lane & 15, s0 = lane >> 4;

  // T1: bijective XCD swizzle (m204)
  const int nwg = gridDim.x;
  const int qq = nwg >> 3, rr8 = nwg & 7, xcd = blockIdx.x & 7, lid = blockIdx.x >> 3;
  const int wg = (xcd < rr8 ? xcd * (qq + 1) : rr8 * (qq + 1) + (xcd - rr8) * qq) + lid;
  const int brow = (wg / NT) * 256, bcol = (wg % NT) * 256;

  // staging: 4 A + 4 B gload_lds16 per thread per K-tile.
  // LDS dest linear: idx = L*512+tid -> row=idx>>3, slot=idx&7.
  // Global source slot inverse-swizzled: src_slot = slot ^ (row&7) (rule 21).
  const unsigned short* ag[4];
  const unsigned short* bg[4];
  #pragma unroll
  for (int L = 0; L < 4; L++) {
    const int idx = L * 512 + tid;
    const int row = idx >> 3;
    const int ss  = ((idx & 7) ^ (row & 7)) * 8;
    ag[L] = A  + (size_t)(brow + row) * K + ss;
    bg[L] = Bw + (size_t)(bcol + row) * K + ss;
  }
  const int ldst = tid * 8;

  #define STG256(kt, buf)                                                     \
    do {                                                                      \
      const int ko = (kt) * 64;                                               \
      gload_lds16(ag[0] + ko, &As[buf][ldst]);                                \
      gload_lds16(ag[1] + ko, &As[buf][4096 + ldst]);                         \
      gload_lds16(ag[2] + ko, &As[buf][8192 + ldst]);                         \
      gload_lds16(ag[3] + ko, &As[buf][12288 + ldst]);                        \
      gload_lds16(bg[0] + ko, &Bs[buf][ldst]);                                \
      gload_lds16(bg[1] + ko, &Bs[buf][4096 + ldst]);                         \
      gload_lds16(bg[2] + ko, &Bs[buf][8192 + ldst]);                         \
      gload_lds16(bg[3] + ko, &Bs[buf][12288 + ldst]);                        \
    } while (0)

  // fragment read offsets (swizzled): elem k in row r lives at slot (k>>3)^(r&7)
  const int xs = fr & 7;
  const int aoff = (wr * 128 + fr) * 64;   // + m*1024 + sl[kk]
  const int boff = (wc * 64 + fr) * 64;    // + n*1024 + sl[kk]
  const int sl0 = ((0 + s0) ^ xs) * 8;
  const int sl1 = ((4 + s0) ^ xs) * 8;

  floatx4 acc[8][4];
  #pragma unroll
  for (int m = 0; m < 8; m++)
    #pragma unroll
    for (int n = 0; n < 4; n++) acc[m][n] = (floatx4){0.f, 0.f, 0.f, 0.f};

  const int NTK = K >> 6;
  STG256(0, 0);

  for (int kt = 0; kt < NTK; ++kt) {
    const int cur = kt & 1;
    if (kt + 1 < NTK) {
      STG256(kt + 1, cur ^ 1);
      asm volatile("s_waitcnt vmcnt(8)" ::: "memory");  // tile kt landed; kt+1 in flight
    } else {
      asm volatile("s_waitcnt vmcnt(0)" ::: "memory");
    }
    __builtin_amdgcn_s_barrier();

    const unsigned short* Ac = As[cur];
    const unsigned short* Bc = Bs[cur];
    short8 a0[4][2], a1[4][2], b0[2][2], b1[2][2];

    // ---- phase 0: read A(m0-3), B(n0-1); MFMA quadrant (m0-3, n0-1)
    #pragma unroll
    for (int m = 0; m < 4; m++) {
      a0[m][0] = *reinterpret_cast<const short8*>(Ac + aoff + m * 1024 + sl0);
      a0[m][1] = *reinterpret_cast<const short8*>(Ac + aoff + m * 1024 + sl1);
    }
    #pragma unroll
    for (int n = 0; n < 2; n++) {
      b0[n][0] = *reinterpret_cast<const short8*>(Bc + boff + n * 1024 + sl0);
      b0[n][1] = *reinterpret_cast<const short8*>(Bc + boff + n * 1024 + sl1);
    }
    __builtin_amdgcn_s_barrier();
    __builtin_amdgcn_s_setprio(1);
    #pragma unroll
    for (int m = 0; m < 4; m++)
      #pragma unroll
      for (int n = 0; n < 2; n++) {
        acc[m][n] = __builtin_amdgcn_mfma_f32_16x16x32_bf16(a0[m][0], b0[n][0], acc[m][n], 0, 0, 0);
        acc[m][n] = __builtin_amdgcn_mfma_f32_16x16x32_bf16(a0[m][1], b0[n][1], acc[m][n], 0, 0, 0);
      }
    __builtin_amdgcn_s_setprio(0);
    __builtin_amdgcn_s_barrier();

    // ---- phase 1: read B(n2-3); MFMA quadrant (m0-3, n2-3)
    #pragma unroll
    for (int n = 0; n < 2; n++) {
      b1[n][0] = *reinterpret_cast<const short8*>(Bc + boff + (n + 2) * 1024 + sl0);
      b1[n][1] = *reinterpret_cast<const short8*>(Bc + boff + (n + 2) * 1024 + sl1);
    }
    __builtin_amdgcn_s_barrier();
    __builtin_amdgcn_s_setprio(1);
    #pragma unroll
    for (int m = 0; m < 4; m++)
      #pragma unroll
      for (int n = 0; n < 2; n++) {
        acc[m][n + 2] = __builtin_amdgcn_mfma_f32_16x16x32_bf16(a0[m][0], b1[n][0], acc[m][n + 2], 0, 0, 0);
        acc[m][n + 2] = __builtin_amdgcn_mfma_f32_16x16x32_bf16(a0[m][1], b1[n][1], acc[m][n + 2], 0, 0, 0);
      }
    __builtin_amdgcn_s_setprio(0);
    __builtin_amdgcn_s_barrier();

    // ---- phase 2: read A(m4-7); MFMA quadrant (m4-7, n0-1)
    #pragma unroll
    for (int m = 0; m < 4; m++) {
      a1[m][0] = *reinterpret_cast<const short8*>(Ac + aoff + (m + 4) * 1024 + sl0);
      a1[m][1] = *reinterpret_cast<const short8*>(Ac + aoff + (m + 4) * 1024 + sl1);
    }
    __builtin_amdgcn_s_barrier();
    __builtin_amdgcn_s_setprio(1);
    #pragma unroll
    for (int m = 0; m < 4; m++)
      #pragma unroll
      for (int n = 0; n < 2; n++) {
        acc[m + 4][n] = __builtin_amdgcn_mfma_f32_16x16x32_bf16(a1[m][0], b0[n][0], acc[m + 4][n], 0, 0, 0);
        acc[m + 4][n] = __builtin_amdgcn_mfma_f32_16x16x32_bf16(a1[m][1], b0[n][1], acc[m + 4][n], 0, 0, 0);
      }
    __builtin_amdgcn_s_setprio(0);
    __builtin_amdgcn_s_barrier();

    // ---- phase 3: MFMA quadrant (m4-7, n2-3); no reads
    __builtin_amdgcn_s_setprio(1);
    #pragma unroll
    for (int m = 0; m < 4; m++)
      #pragma unroll
      for (int n = 0; n < 2; n++) {
        acc[m + 4][n + 2] = __builtin_amdgcn_mfma_f32_16x16x32_bf16(a1[m][0], b1[n][0], acc[m + 4][n + 2], 0, 0, 0);
        acc[m + 4][n + 2] = __builtin_amdgcn_mfma_f32_16x16x32_bf16(a1[m][1], b1[n][1], acc[m + 4][n + 2], 0, 0, 0);
      }
    __builtin_amdgcn_s_setprio(0);
    __builtin_amdgcn_s_barrier();   // all reads of 'cur' done before next tile stages into it
  }
  #undef STG256

  // epilogue
  #pragma unroll
  for (int m = 0; m < 8; m++) {
    #pragma unroll
    for (int n = 0; n < 4; n++) {
      const int col = bcol + wc * 64 + n * 16 + fr;
      #pragma unroll
      for (int r = 0; r < 4; r++) {
        const size_t idx = (size_t)(brow + wr * 128 + m * 16 + s0 * 4 + r) * N + col;
        float v = acc[m][n][r];
        if (EPI == 1) {
          v += bias[col];
          const float u = v * 0.7978845608f * (1.0f + 0.044715f * v * v);
          const float e = __expf(2.0f * u);
          v = v * (e / (e + 1.0f));   // x * sigmoid(2u) == 0.5x(1+tanh u)
        }
        outb[idx] = f2bf(v);
      }
    }
  }
}

// ============ gemm128: 128x128 tile, BK=32, 4-buffer ring (3 tiles prefetched) ============
// 1 block/CU grids are latency-bound with 2-deep pipelines (R3: 1600 cy/K-step);
// depth-3 prefetch gives ~900 cy slack = HBM latency. Swizzle uses (fr>>1)&3:
// 64B rows alternate bank halves by row parity, so bits [2:1] must feed the XOR
// (fr&3 left a 4-way conflict = R3's 4.19M cycles).
// EPI 0: store bf16. EPI 2: +bias +resid, store f32.
template<int EPI>
__global__ __launch_bounds__(256) void gemm128(const unsigned short* __restrict__ A,
                                               const unsigned short* __restrict__ Bw,
                                               unsigned short* __restrict__ outb,
                                               float* __restrict__ outf,
                                               const float* __restrict__ bias,
                                               const float* __restrict__ resid,
                                               int K, int N, int NT) {
  __shared__ unsigned short As[4][128 * 32];
  __shared__ unsigned short Bs[4][128 * 32];
  const int tid = threadIdx.x, lane = tid & 63, wid = tid >> 6;
  const int wrow = (wid >> 1) * 64, wcol = (wid & 1) * 64;
  const int fr = lane & 15, s0 = lane >> 4;

  // T1 bijective XCD swizzle
  const int nwg = gridDim.x;
  const int qq = nwg >> 3, rr8 = nwg & 7, xcd = blockIdx.x & 7, lid = blockIdx.x >> 3;
  const int wg = (xcd < rr8 ? xcd * (qq + 1) : rr8 * (qq + 1) + (xcd - rr8) * qq) + lid;
  const int brow = (wg / NT) * 128, bcol = (wg % NT) * 128;

  // staging: 2 A + 2 B loads/thread; idx = L*256+tid -> row=idx>>2, slot=idx&3
  const unsigned short* ag[2];
  const unsigned short* bg[2];
  #pragma unroll
  for (int L = 0; L < 2; L++) {
    const int idx = L * 256 + tid;
    const int row = idx >> 2;
    const int ss  = ((idx & 3) ^ ((row >> 1) & 3)) * 8;   // inverse of read swizzle
    ag[L] = A  + (size_t)(brow + row) * K + ss;
    bg[L] = Bw + (size_t)(bcol + row) * K + ss;
  }
  const int ldst = tid * 8;

  #define STG128(kt, buf)                                 \
    do {                                                  \
      const int ko = (kt) * 32;                           \
      gload_lds16(ag[0] + ko, &As[buf][ldst]);            \
      gload_lds16(ag[1] + ko, &As[buf][2048 + ldst]);     \
      gload_lds16(bg[0] + ko, &Bs[buf][ldst]);            \
      gload_lds16(bg[1] + ko, &Bs[buf][2048 + ldst]);     \
    } while (0)

  const int slr = (s0 ^ ((fr >> 1) & 3)) * 8;   // swizzled k-slot for fragment reads

  floatx4 acc[4][4];
  #pragma unroll
  for (int i = 0; i < 4; i++)
    #pragma unroll
    for (int j = 0; j < 4; j++) acc[i][j] = (floatx4){0.f, 0.f, 0.f, 0.f};

  const int NTK = K >> 5;
  STG128(0, 0);
  STG128(1, 1);
  STG128(2, 2);

  for (int kt = 0; kt < NTK; ++kt) {
    const int cur = kt & 3;
    if (kt + 3 < NTK) {
      STG128(kt + 3, (kt + 3) & 3);
      asm volatile("s_waitcnt vmcnt(12)" ::: "memory");  // tile kt done; kt+1..kt+3 in flight
    } else if (kt + 2 < NTK) {
      asm volatile("s_waitcnt vmcnt(8)" ::: "memory");
    } else if (kt + 1 < NTK) {
      asm volatile("s_waitcnt vmcnt(4)" ::: "memory");
    } else {
      asm volatile("s_waitcnt vmcnt(0)" ::: "memory");
    }
    __builtin_amdgcn_s_barrier();

    short8 af[4], bf[4];
    #pragma unroll
    for (int i = 0; i < 4; i++)
      af[i] = *reinterpret_cast<const short8*>(&As[cur][(wrow + i * 16 + fr) * 32 + slr]);
    #pragma unroll
    for (int j = 0; j < 4; j++)
      bf[j] = *reinterpret_cast<const short8*>(&Bs[cur][(wcol + j * 16 + fr) * 32 + slr]);
    __builtin_amdgcn_s_setprio(1);
    #pragma unroll
    for (int i = 0; i < 4; i++)
      #pragma unroll
      for (int j = 0; j < 4; j++)
        acc[i][j] = __builtin_amdgcn_mfma_f32_16x16x32_bf16(af[i], bf[j], acc[i][j], 0, 0, 0);
    __builtin_amdgcn_s_setprio(0);
    __builtin_amdgcn_s_barrier();  // readers done before next iter stages into buf (kt+4)&3 == cur
  }
  #undef STG128

  const int erow = brow + wrow + (s0 << 2);
  const int ecol = bcol + wcol + fr;
  #pragma unroll
  for (int i = 0; i < 4; i++) {
    #pragma unroll
    for (int j = 0; j < 4; j++) {
      const int col = ecol + j * 16;
      #pragma unroll
      for (int r = 0; r < 4; r++) {
        const size_t idx = (size_t)(erow + i * 16 + r) * N + col;
        float v = acc[i][j][r];
        if (EPI == 0) {
          outb[idx] = f2bf(v);
        } else if (EPI == 2) {
          v += bias[col] + resid[idx];
          outf[idx] = v;
        }
      }
    }
  }
}

// ---------------- V transpose: qkv[b*1024+n][2048+h*64+d] -> vt[(bh*64+d)*1024+n] ----------------
__global__ __launch_bounds__(256) void vtrans_kernel(const unsigned short* __restrict__ qkv,
                                                     unsigned short* __restrict__ vt) {
  __shared__ unsigned short T[64][66];   // [n_local][d], +2 pad
  const int nt = blockIdx.x, bh = blockIdx.y;
  const int b = bh >> 4, h = bh & 15;
  const unsigned short* src = qkv + (size_t)b * 1024 * 3072 + 2048 + h * 64;
  const int r = threadIdx.x >> 3, s = threadIdx.x & 7;
  ushort8 a0 = *reinterpret_cast<const ushort8*>(src + (size_t)(nt * 64 + r) * 3072 + s * 8);
  ushort8 a1 = *reinterpret_cast<const ushort8*>(src + (size_t)(nt * 64 + r + 32) * 3072 + s * 8);
  #pragma unroll
  for (int j = 0; j < 8; j++) {
    T[r][s * 8 + j]      = a0[j];
    T[r + 32][s * 8 + j] = a1[j];
  }
  __syncthreads();
  ushort8 o0, o1;
  #pragma unroll
  for (int j = 0; j < 8; j++) {
    o0[j] = T[s * 8 + j][r];
    o1[j] = T[s * 8 + j][r + 32];
  }
  unsigned short* dst = vt + (size_t)bh * 64 * 1024 + nt * 64 + s * 8;
  *reinterpret_cast<ushort8*>(dst + (size_t)r * 1024)        = o0;
  *reinterpret_cast<ushort8*>(dst + (size_t)(r + 32) * 1024) = o1;
}

// ---------------- Flash attention ----------------
// qkv: bf16 [B*N][3072] (q at col h*64, k at 1024+h*64); vt: bf16 [bh][64 d][1024 n]
// y:   bf16 [B*N][1024]
__global__ __launch_bounds__(256) void attn_kernel(const unsigned short* __restrict__ qkv,
                                                   const unsigned short* __restrict__ vt,
                                                   unsigned short* __restrict__ y) {
  __shared__ unsigned short Ks[2][64 * 64];  // [kv][d], slot-swizzled
  __shared__ unsigned short Vs[2][64 * 64];  // [d][kv], slot-swizzled
  __shared__ unsigned short Ps[4][16 * 64];  // per-wave [q][kv], swizzled

  const int tid = threadIdx.x;
  const int lane = tid & 63;
  const int w = tid >> 6;
  // XCD-aware bijective swizzle: 1024 blocks, 8 XCDs -> 16 qt of one bh stay on one XCD
  const int wg = (blockIdx.x & 7) * 128 + (blockIdx.x >> 3);
  const int bh = wg >> 4, qt = wg & 15;
  const int b = bh >> 4, h = bh & 15;
  const int fr = lane & 15, s0 = lane >> 4;
  const int fk = s0 * 8;
  const int sw = fr & 7;
  const size_t RS = 3072;

  const unsigned short* qbase = qkv + (size_t)b * 1024 * RS + h * 64;
  const unsigned short* kbase = qbase + 1024;
  const unsigned short* vbase = vt + (size_t)bh * 64 * 1024;

  // Q fragments (held for whole kernel)
  short8 aq[2];
  {
    const unsigned short* qrow = qbase + (size_t)(qt * 64 + w * 16 + fr) * RS;
    aq[0] = *reinterpret_cast<const short8*>(qrow + fk);
    aq[1] = *reinterpret_cast<const short8*>(qrow + 32 + fk);
  }

  float m_run[4], l_run[4];
  floatx4 accy[4];
  #pragma unroll
  for (int r = 0; r < 4; r++) { m_run[r] = -1e30f; l_run[r] = 0.f; }
  #pragma unroll
  for (int d = 0; d < 4; d++) accy[d] = (floatx4){0.f, 0.f, 0.f, 0.f};

  // staging geometry: row = tid>>3 (+32), 16B slot = tid&7; source slot inverse-swizzled
  const int krow0 = tid >> 3, kslot = tid & 7;
  const int gslot = (kslot ^ (krow0 & 7)) * 8;
  const unsigned short* kg0 = kbase + (size_t)krow0 * RS + gslot;
  const unsigned short* kg1 = kbase + (size_t)(krow0 + 32) * RS + gslot;
  const unsigned short* vg0 = vbase + (size_t)krow0 * 1024 + gslot;
  const unsigned short* vg1 = vbase + (size_t)(krow0 + 32) * 1024 + gslot;

  #define STAGE(t, buf)                                          \
    do {                                                         \
      const size_t ko = (size_t)(t) * 64 * RS;                   \
      const size_t vo = (size_t)(t) * 64;                        \
      gload_lds16(kg0 + ko, &Ks[buf][tid * 8]);                  \
      gload_lds16(kg1 + ko, &Ks[buf][(256 + tid) * 8]);          \
      gload_lds16(vg0 + vo, &Vs[buf][tid * 8]);                  \
      gload_lds16(vg1 + vo, &Vs[buf][(256 + tid) * 8]);          \
    } while (0)

  STAGE(0, 0);
  int cur = 0;

  for (int kt = 0; kt < 16; ++kt) {
    if (kt < 15) {
      STAGE(kt + 1, cur ^ 1);
      asm volatile("s_waitcnt vmcnt(4)" ::: "memory");
    } else {
      asm volatile("s_waitcnt vmcnt(0)" ::: "memory");
    }
    __builtin_amdgcn_s_barrier();

    const unsigned short* Kt = Ks[cur];
    const unsigned short* Vc = Vs[cur];

    // S = scale * Q K^T (16 q-rows x 64 kv)
    floatx4 sfr[4];
    #pragma unroll
    for (int f = 0; f < 4; ++f) {
      floatx4 s = (floatx4){0.f, 0.f, 0.f, 0.f};
      const unsigned short* krow = Kt + (f * 16 + fr) * 64;
      short8 kb0 = *reinterpret_cast<const short8*>(krow + (((s0)     ^ sw) << 3));
      short8 kb1 = *reinterpret_cast<const short8*>(krow + (((s0 + 4) ^ sw) << 3));
      s = __builtin_amdgcn_mfma_f32_16x16x32_bf16(aq[0], kb0, s, 0, 0, 0);
      s = __builtin_amdgcn_mfma_f32_16x16x32_bf16(aq[1], kb1, s, 0, 0, 0);
      sfr[f] = s * 0.125f;
    }

    // online softmax (rows live on 16-lane groups)
    #pragma unroll
    for (int r = 0; r < 4; r++) {
      float mv = fmaxf(fmaxf(sfr[0][r], sfr[1][r]), fmaxf(sfr[2][r], sfr[3][r]));
      #pragma unroll
      for (int m = 1; m < 16; m <<= 1) mv = fmaxf(mv, __shfl_xor(mv, m));
      const float mn = fmaxf(m_run[r], mv);
      const float alpha = __expf(m_run[r] - mn);
      m_run[r] = mn;
      const int q = s0 * 4 + r;
      const int qx = (q & 7) << 3;
      float ps = 0.f;
      #pragma unroll
      for (int f = 0; f < 4; f++) {
        float p = __expf(sfr[f][r] - mn);
        ps += p;
        Ps[w][q * 64 + ((f * 16 + fr) ^ qx)] = f2bf(p);
      }
      #pragma unroll
      for (int m = 1; m < 16; m <<= 1) ps += __shfl_xor(ps, m);
      l_run[r] = l_run[r] * alpha + ps;
      #pragma unroll
      for (int d = 0; d < 4; d++) accy[d][r] *= alpha;
    }

    // Y += P V   (A = P rows q, B = V^T rows d, contract over kv)
    #pragma unroll
    for (int ks = 0; ks < 2; ++ks) {
      const int sA = ((ks * 4 + s0) ^ sw) << 3;
      short8 ap = *reinterpret_cast<const short8*>(&Ps[w][fr * 64 + sA]);
      #pragma unroll
      for (int j = 0; j < 4; ++j) {
        short8 vb = *reinterpret_cast<const short8*>(Vc + (j * 16 + fr) * 64 + sA);
        accy[j] = __builtin_amdgcn_mfma_f32_16x16x32_bf16(ap, vb, accy[j], 0, 0, 0);
      }
    }
    __builtin_amdgcn_s_barrier();
    cur ^= 1;
  }
  #undef STAGE

  // write y (bf16) into [B*N][1024] at col h*64
  #pragma unroll
  for (int r = 0; r < 4; r++) {
    const float inv = 1.0f / l_run[r];
    const size_t grow =
        (size_t)(b * 1024 + qt * 64 + w * 16 + s0 * 4 + r) * 1024 + h * 64;
    #pragma unroll
    for (int d = 0; d < 4; ++d)
      y[grow + d * 16 + fr] = f2bf(accy[d][r] * inv);
  }
}

// ---------------- launcher ----------------
extern "C" void kernel_launch(void* const* d_in, const int* in_sizes, int n_in,
                              void* d_out, int out_size, void* d_ws, size_t ws_size,
                              hipStream_t stream) {
  const float* x      = (const float*)d_in[0];
  const float* qkv_w  = (const float*)d_in[1];
  const float* proj_w = (const float*)d_in[2];
  const float* proj_b = (const float*)d_in[3];
  const float* ln1_w  = (const float*)d_in[4];
  const float* ln1_b  = (const float*)d_in[5];
  const float* fc1_w  = (const float*)d_in[6];
  const float* fc1_b  = (const float*)d_in[7];
  const float* fc2_w  = (const float*)d_in[8];
  const float* fc2_b  = (const float*)d_in[9];
  const float* ln2_w  = (const float*)d_in[10];
  const float* ln2_b  = (const float*)d_in[11];
  float* out = (float*)d_out;

  char* ws = (char*)d_ws;
  unsigned short* qkvw16  = (unsigned short*)(ws + 0);          //  6.0 MB
  unsigned short* projw16 = (unsigned short*)(ws + 6291456);    //  2.0 MB
  unsigned short* fc1w16  = (unsigned short*)(ws + 8388608);    //  8.0 MB
  unsigned short* fc2w16  = (unsigned short*)(ws + 16777216);   //  8.0 MB
  float*          x1      = (float*)(ws + 25165824);            // 16.0 MB f32 (after attn)
  unsigned short* vt      = (unsigned short*)(ws + 25165824);   //  8.0 MB (dead before x1 written)
  unsigned short* xn      = (unsigned short*)(ws + 41943040);   //  8.0 MB (xn1 / y / xn2)
  unsigned short* big     = (unsigned short*)(ws + 50331648);   // 32.0 MB (qkvout / h)

  // weights -> bf16
  cvt_kernel<<<3072, 256, 0, stream>>>(qkv_w,  qkvw16, 786432);
  cvt_kernel<<<1024, 256, 0, stream>>>(proj_w, projw16, 262144);
  cvt_kernel<<<4096, 256, 0, stream>>>(fc1_w,  fc1w16, 1048576);
  cvt_kernel<<<4096, 256, 0, stream>>>(fc2_w,  fc2w16, 1048576);

  // LN1: x -> xn (bf16)
  ln_kernel<<<4096, 256, 0, stream>>>(x, ln1_w, ln1_b, xn);
  // qkv = xn * qkv_w^T  -> big (bf16 [4096][3072]); 16x12 = 192 blocks
  gemm256<0><<<192, 512, 0, stream>>>(xn, qkvw16, big, nullptr, 1024, 3072, 12);
  // V^T per head -> vt
  vtrans_kernel<<<dim3(16, 64), 256, 0, stream>>>(big, vt);
  // attention: big + vt -> xn (y, bf16 [4096][1024])
  attn_kernel<<<1024, 256, 0, stream>>>(big, vt, xn);
  // x1 = y * proj_w^T + proj_b + x  (f32); 32x8 = 256 blocks
  gemm128<2><<<256, 256, 0, stream>>>(xn, projw16, nullptr, x1, proj_b, x, 1024, 1024, 8);
  // LN2: x1 -> xn (bf16)
  ln_kernel<<<4096, 256, 0, stream>>>(x1, ln2_w, ln2_b, xn);
  // h = gelu(xn * fc1_w^T + fc1_b) -> big (bf16 [4096][4096]); 16x16 = 256 blocks
  gemm256<1><<<256, 512, 0, stream>>>(xn, fc1w16, big, fc1_b, 1024, 4096, 16);
  // out = h * fc2_w^T + fc2_b + x1  (f32); 32x8 = 256 blocks
  gemm128<2><<<256, 256, 0, stream>>>(big, fc2w16, nullptr, out, fc2_b, x1, 4096, 1024, 8);
}

// Round 5
// 266.383 us; speedup vs baseline: 1.3461x; 1.0729x over previous
//
#include <hip/hip_runtime.h>
#include <hip/hip_bf16.h>

typedef __attribute__((ext_vector_type(8))) short short8;
typedef __attribute__((ext_vector_type(8))) unsigned short ushort8;
typedef __attribute__((ext_vector_type(4))) float floatx4;

#define DEV static __device__ __forceinline__

DEV unsigned short f2bf(float f) {
  unsigned int u = __builtin_bit_cast(unsigned int, f);
  u += 0x7fff + ((u >> 16) & 1);   // round-to-nearest-even (no NaN inputs here)
  return (unsigned short)(u >> 16);
}

DEV void gload_lds16(const void* g, void* l) {
  __builtin_amdgcn_global_load_lds(
      (const __attribute__((address_space(1))) unsigned int*)g,
      (__attribute__((address_space(3))) unsigned int*)l, 16, 0, 0);
}

// ---------------- f32 -> bf16 converter (weights) ----------------
__global__ __launch_bounds__(256) void cvt_kernel(const float* __restrict__ in,
                                                  unsigned short* __restrict__ out,
                                                  int n4) {
  int i = blockIdx.x * 256 + threadIdx.x;
  if (i >= n4) return;
  float4 v = reinterpret_cast<const float4*>(in)[i];
  ushort4 o;
  o.x = f2bf(v.x); o.y = f2bf(v.y); o.z = f2bf(v.z); o.w = f2bf(v.w);
  reinterpret_cast<ushort4*>(out)[i] = o;
}

// ---------------- LayerNorm: f32 [rows][1024] -> bf16 ----------------
__global__ __launch_bounds__(256) void ln_kernel(const float* __restrict__ x,
                                                 const float* __restrict__ w,
                                                 const float* __restrict__ b,
                                                 unsigned short* __restrict__ out) {
  const int row = blockIdx.x;
  const float* xr = x + (size_t)row * 1024;
  float4 v = reinterpret_cast<const float4*>(xr)[threadIdx.x];
  float s  = v.x + v.y + v.z + v.w;
  float ss = v.x*v.x + v.y*v.y + v.z*v.z + v.w*v.w;
  #pragma unroll
  for (int off = 1; off < 64; off <<= 1) {
    s  += __shfl_xor(s, off);
    ss += __shfl_xor(ss, off);
  }
  __shared__ float red[8];
  const int wid = threadIdx.x >> 6, lane = threadIdx.x & 63;
  if (lane == 0) { red[wid] = s; red[4 + wid] = ss; }
  __syncthreads();
  s  = red[0] + red[1] + red[2] + red[3];
  ss = red[4] + red[5] + red[6] + red[7];
  const float mu  = s * (1.0f / 1024.0f);
  const float var = ss * (1.0f / 1024.0f) - mu * mu;
  const float rstd = rsqrtf(var + 1e-5f);
  float4 wv = reinterpret_cast<const float4*>(w)[threadIdx.x];
  float4 bv = reinterpret_cast<const float4*>(b)[threadIdx.x];
  ushort4 o;
  o.x = f2bf((v.x - mu) * rstd * wv.x + bv.x);
  o.y = f2bf((v.y - mu) * rstd * wv.y + bv.y);
  o.z = f2bf((v.z - mu) * rstd * wv.z + bv.z);
  o.w = f2bf((v.w - mu) * rstd * wv.w + bv.w);
  reinterpret_cast<ushort4*>(out)[(size_t)row * 256 + threadIdx.x] = o;
}

// ============ gemm256: C[M,N] = A[M,K] * B[N,K]^T, 256x256 tile, BK=64 ============
// 512 threads, 8 waves (2 M x 4 N), per-wave 128x64 out. Double-buffered 128KB LDS,
// counted vmcnt(8) pipeline, slot-XOR swizzle, 4-phase MFMA interleave + setprio.
// EPI 0: store bf16. EPI 1: +bias, tanh-GELU, store bf16.
template<int EPI>
__global__ __launch_bounds__(512, 2) void gemm256(const unsigned short* __restrict__ A,
                                                  const unsigned short* __restrict__ Bw,
                                                  unsigned short* __restrict__ outb,
                                                  const float* __restrict__ bias,
                                                  int K, int N, int NT) {
  __shared__ unsigned short As[2][256 * 64];
  __shared__ unsigned short Bs[2][256 * 64];
  const int tid = threadIdx.x, lane = tid & 63, wid = tid >> 6;
  const int wr = wid >> 2, wc = wid & 3;
  const int fr = lane & 15, s0 = lane >> 4;

  // T1: bijective XCD swizzle (m204)
  const int nwg = gridDim.x;
  const int qq = nwg >> 3, rr8 = nwg & 7, xcd = blockIdx.x & 7, lid = blockIdx.x >> 3;
  const int wg = (xcd < rr8 ? xcd * (qq + 1) : rr8 * (qq + 1) + (xcd - rr8) * qq) + lid;
  const int brow = (wg / NT) * 256, bcol = (wg % NT) * 256;

  // staging: 4 A + 4 B gload_lds16 per thread per K-tile.
  // LDS dest linear: idx = L*512+tid -> row=idx>>3, slot=idx&7.
  // Global source slot inverse-swizzled: src_slot = slot ^ (row&7) (rule 21).
  const unsigned short* ag[4];
  const unsigned short* bg[4];
  #pragma unroll
  for (int L = 0; L < 4; L++) {
    const int idx = L * 512 + tid;
    const int row = idx >> 3;
    const int ss  = ((idx & 7) ^ (row & 7)) * 8;
    ag[L] = A  + (size_t)(brow + row) * K + ss;
    bg[L] = Bw + (size_t)(bcol + row) * K + ss;
  }
  const int ldst = tid * 8;

  #define STG256(kt, buf)                                                     \
    do {                                                                      \
      const int ko = (kt) * 64;                                               \
      gload_lds16(ag[0] + ko, &As[buf][ldst]);                                \
      gload_lds16(ag[1] + ko, &As[buf][4096 + ldst]);                         \
      gload_lds16(ag[2] + ko, &As[buf][8192 + ldst]);                         \
      gload_lds16(ag[3] + ko, &As[buf][12288 + ldst]);                        \
      gload_lds16(bg[0] + ko, &Bs[buf][ldst]);                                \
      gload_lds16(bg[1] + ko, &Bs[buf][4096 + ldst]);                         \
      gload_lds16(bg[2] + ko, &Bs[buf][8192 + ldst]);                         \
      gload_lds16(bg[3] + ko, &Bs[buf][12288 + ldst]);                        \
    } while (0)

  // fragment read offsets (swizzled): elem k in row r lives at slot (k>>3)^(r&7)
  const int xs = fr & 7;
  const int aoff = (wr * 128 + fr) * 64;   // + m*1024 + sl[kk]
  const int boff = (wc * 64 + fr) * 64;    // + n*1024 + sl[kk]
  const int sl0 = ((0 + s0) ^ xs) * 8;
  const int sl1 = ((4 + s0) ^ xs) * 8;

  floatx4 acc[8][4];
  #pragma unroll
  for (int m = 0; m < 8; m++)
    #pragma unroll
    for (int n = 0; n < 4; n++) acc[m][n] = (floatx4){0.f, 0.f, 0.f, 0.f};

  const int NTK = K >> 6;
  STG256(0, 0);

  for (int kt = 0; kt < NTK; ++kt) {
    const int cur = kt & 1;
    if (kt + 1 < NTK) {
      STG256(kt + 1, cur ^ 1);
      asm volatile("s_waitcnt vmcnt(8)" ::: "memory");  // tile kt landed; kt+1 in flight
    } else {
      asm volatile("s_waitcnt vmcnt(0)" ::: "memory");
    }
    __builtin_amdgcn_s_barrier();

    const unsigned short* Ac = As[cur];
    const unsigned short* Bc = Bs[cur];
    short8 a0[4][2], a1[4][2], b0[2][2], b1[2][2];

    // ---- phase 0: read A(m0-3), B(n0-1); MFMA quadrant (m0-3, n0-1)
    #pragma unroll
    for (int m = 0; m < 4; m++) {
      a0[m][0] = *reinterpret_cast<const short8*>(Ac + aoff + m * 1024 + sl0);
      a0[m][1] = *reinterpret_cast<const short8*>(Ac + aoff + m * 1024 + sl1);
    }
    #pragma unroll
    for (int n = 0; n < 2; n++) {
      b0[n][0] = *reinterpret_cast<const short8*>(Bc + boff + n * 1024 + sl0);
      b0[n][1] = *reinterpret_cast<const short8*>(Bc + boff + n * 1024 + sl1);
    }
    __builtin_amdgcn_s_barrier();
    __builtin_amdgcn_s_setprio(1);
    #pragma unroll
    for (int m = 0; m < 4; m++)
      #pragma unroll
      for (int n = 0; n < 2; n++) {
        acc[m][n] = __builtin_amdgcn_mfma_f32_16x16x32_bf16(a0[m][0], b0[n][0], acc[m][n], 0, 0, 0);
        acc[m][n] = __builtin_amdgcn_mfma_f32_16x16x32_bf16(a0[m][1], b0[n][1], acc[m][n], 0, 0, 0);
      }
    __builtin_amdgcn_s_setprio(0);
    __builtin_amdgcn_s_barrier();

    // ---- phase 1: read B(n2-3); MFMA quadrant (m0-3, n2-3)
    #pragma unroll
    for (int n = 0; n < 2; n++) {
      b1[n][0] = *reinterpret_cast<const short8*>(Bc + boff + (n + 2) * 1024 + sl0);
      b1[n][1] = *reinterpret_cast<const short8*>(Bc + boff + (n + 2) * 1024 + sl1);
    }
    __builtin_amdgcn_s_barrier();
    __builtin_amdgcn_s_setprio(1);
    #pragma unroll
    for (int m = 0; m < 4; m++)
      #pragma unroll
      for (int n = 0; n < 2; n++) {
        acc[m][n + 2] = __builtin_amdgcn_mfma_f32_16x16x32_bf16(a0[m][0], b1[n][0], acc[m][n + 2], 0, 0, 0);
        acc[m][n + 2] = __builtin_amdgcn_mfma_f32_16x16x32_bf16(a0[m][1], b1[n][1], acc[m][n + 2], 0, 0, 0);
      }
    __builtin_amdgcn_s_setprio(0);
    __builtin_amdgcn_s_barrier();

    // ---- phase 2: read A(m4-7); MFMA quadrant (m4-7, n0-1)
    #pragma unroll
    for (int m = 0; m < 4; m++) {
      a1[m][0] = *reinterpret_cast<const short8*>(Ac + aoff + (m + 4) * 1024 + sl0);
      a1[m][1] = *reinterpret_cast<const short8*>(Ac + aoff + (m + 4) * 1024 + sl1);
    }
    __builtin_amdgcn_s_barrier();
    __builtin_amdgcn_s_setprio(1);
    #pragma unroll
    for (int m = 0; m < 4; m++)
      #pragma unroll
      for (int n = 0; n < 2; n++) {
        acc[m + 4][n] = __builtin_amdgcn_mfma_f32_16x16x32_bf16(a1[m][0], b0[n][0], acc[m + 4][n], 0, 0, 0);
        acc[m + 4][n] = __builtin_amdgcn_mfma_f32_16x16x32_bf16(a1[m][1], b0[n][1], acc[m + 4][n], 0, 0, 0);
      }
    __builtin_amdgcn_s_setprio(0);
    __builtin_amdgcn_s_barrier();

    // ---- phase 3: MFMA quadrant (m4-7, n2-3); no reads
    __builtin_amdgcn_s_setprio(1);
    #pragma unroll
    for (int m = 0; m < 4; m++)
      #pragma unroll
      for (int n = 0; n < 2; n++) {
        acc[m + 4][n + 2] = __builtin_amdgcn_mfma_f32_16x16x32_bf16(a1[m][0], b1[n][0], acc[m + 4][n + 2], 0, 0, 0);
        acc[m + 4][n + 2] = __builtin_amdgcn_mfma_f32_16x16x32_bf16(a1[m][1], b1[n][1], acc[m + 4][n + 2], 0, 0, 0);
      }
    __builtin_amdgcn_s_setprio(0);
    __builtin_amdgcn_s_barrier();   // all reads of 'cur' done before next tile stages into it
  }
  #undef STG256

  // epilogue
  #pragma unroll
  for (int m = 0; m < 8; m++) {
    #pragma unroll
    for (int n = 0; n < 4; n++) {
      const int col = bcol + wc * 64 + n * 16 + fr;
      #pragma unroll
      for (int r = 0; r < 4; r++) {
        const size_t idx = (size_t)(brow + wr * 128 + m * 16 + s0 * 4 + r) * N + col;
        float v = acc[m][n][r];
        if (EPI == 1) {
          v += bias[col];
          const float u = v * 0.7978845608f * (1.0f + 0.044715f * v * v);
          const float e = __expf(2.0f * u);
          v = v * (e / (e + 1.0f));   // x * sigmoid(2u) == 0.5x(1+tanh u)
        }
        outb[idx] = f2bf(v);
      }
    }
  }
}

// ============ gemm128w8: 128x128 tile, BK=64, 512 threads (8 waves, 2x4) ============
// R4 post-mortem: at grid 256 = 1 block/CU, 256-thread blocks leave 1 wave/SIMD and
// every ds_read/barrier latency is exposed (1520 cy/K-step measured vs ~400 model).
// Fix: 8 waves -> 2 waves/SIMD for intra-CU overlap; BK=64 halves barrier count.
// 3-buffer ring, depth-2 prefetch, counted vmcnt 8 -> 4 -> 0 (4 loads/wave/tile).
// EPI 0: store bf16. EPI 2: +bias +resid, store f32.
template<int EPI>
__global__ __launch_bounds__(512) void gemm128w8(const unsigned short* __restrict__ A,
                                                 const unsigned short* __restrict__ Bw,
                                                 unsigned short* __restrict__ outb,
                                                 float* __restrict__ outf,
                                                 const float* __restrict__ bias,
                                                 const float* __restrict__ resid,
                                                 int K, int N, int NT) {
  __shared__ unsigned short As[3][128 * 64];
  __shared__ unsigned short Bs[3][128 * 64];
  const int tid = threadIdx.x, lane = tid & 63, wid = tid >> 6;
  const int wrow = (wid >> 2) * 64, wcol = (wid & 3) * 32;
  const int fr = lane & 15, s0 = lane >> 4;

  // T1 bijective XCD swizzle
  const int nwg = gridDim.x;
  const int qq = nwg >> 3, rr8 = nwg & 7, xcd = blockIdx.x & 7, lid = blockIdx.x >> 3;
  const int wg = (xcd < rr8 ? xcd * (qq + 1) : rr8 * (qq + 1) + (xcd - rr8) * qq) + lid;
  const int brow = (wg / NT) * 128, bcol = (wg % NT) * 128;

  // staging: 2 A + 2 B loads/thread; idx = L*512+tid -> row=idx>>3, 16B slot=idx&7
  // source slot inverse-swizzled: src_slot = slot ^ (row&7) (rule 21)
  const unsigned short* ag[2];
  const unsigned short* bg[2];
  #pragma unroll
  for (int L = 0; L < 2; L++) {
    const int idx = L * 512 + tid;
    const int row = idx >> 3;
    const int ss  = ((idx & 7) ^ (row & 7)) * 8;
    ag[L] = A  + (size_t)(brow + row) * K + ss;
    bg[L] = Bw + (size_t)(bcol + row) * K + ss;
  }
  const int ldst = tid * 8;

  #define STG128(kt, buf)                                 \
    do {                                                  \
      const int ko = (kt) * 64;                           \
      gload_lds16(ag[0] + ko, &As[buf][ldst]);            \
      gload_lds16(ag[1] + ko, &As[buf][4096 + ldst]);     \
      gload_lds16(bg[0] + ko, &Bs[buf][ldst]);            \
      gload_lds16(bg[1] + ko, &Bs[buf][4096 + ldst]);     \
    } while (0)

  // fragment reads: elem-block kk (8 bf16) of row r lives at slot (kk)^(r&7)
  const int xs = fr & 7;
  const int sl0 = ((0 + s0) ^ xs) * 8;
  const int sl1 = ((4 + s0) ^ xs) * 8;
  const int aoff = (wrow + fr) * 64;
  const int boff = (wcol + fr) * 64;

  floatx4 acc[4][2];
  #pragma unroll
  for (int i = 0; i < 4; i++)
    #pragma unroll
    for (int j = 0; j < 2; j++) acc[i][j] = (floatx4){0.f, 0.f, 0.f, 0.f};

  const int NTK = K >> 6;
  STG128(0, 0);
  STG128(1, 1);
  int cur = 0, stg = 2;

  for (int kt = 0; kt < NTK; ++kt) {
    if (kt + 2 < NTK) {
      STG128(kt + 2, stg);
      stg = (stg == 2) ? 0 : stg + 1;
      asm volatile("s_waitcnt vmcnt(8)" ::: "memory");  // tile kt landed; kt+1,kt+2 in flight
    } else if (kt + 1 < NTK) {
      asm volatile("s_waitcnt vmcnt(4)" ::: "memory");
    } else {
      asm volatile("s_waitcnt vmcnt(0)" ::: "memory");
    }
    __builtin_amdgcn_s_barrier();

    const unsigned short* Ac = As[cur];
    const unsigned short* Bc = Bs[cur];
    short8 af[4][2], bf[2][2];
    #pragma unroll
    for (int i = 0; i < 4; i++) {
      af[i][0] = *reinterpret_cast<const short8*>(Ac + aoff + i * 1024 + sl0);
      af[i][1] = *reinterpret_cast<const short8*>(Ac + aoff + i * 1024 + sl1);
    }
    #pragma unroll
    for (int j = 0; j < 2; j++) {
      bf[j][0] = *reinterpret_cast<const short8*>(Bc + boff + j * 1024 + sl0);
      bf[j][1] = *reinterpret_cast<const short8*>(Bc + boff + j * 1024 + sl1);
    }
    __builtin_amdgcn_s_setprio(1);
    #pragma unroll
    for (int i = 0; i < 4; i++)
      #pragma unroll
      for (int j = 0; j < 2; j++) {
        acc[i][j] = __builtin_amdgcn_mfma_f32_16x16x32_bf16(af[i][0], bf[j][0], acc[i][j], 0, 0, 0);
        acc[i][j] = __builtin_amdgcn_mfma_f32_16x16x32_bf16(af[i][1], bf[j][1], acc[i][j], 0, 0, 0);
      }
    __builtin_amdgcn_s_setprio(0);
    __builtin_amdgcn_s_barrier();  // readers done before next iter stages into cur's ring slot
    cur = (cur == 2) ? 0 : cur + 1;
  }
  #undef STG128

  const int erow = brow + wrow + (s0 << 2);
  const int ecol = bcol + wcol + fr;
  #pragma unroll
  for (int i = 0; i < 4; i++) {
    #pragma unroll
    for (int j = 0; j < 2; j++) {
      const int col = ecol + j * 16;
      #pragma unroll
      for (int r = 0; r < 4; r++) {
        const size_t idx = (size_t)(erow + i * 16 + r) * N + col;
        float v = acc[i][j][r];
        if (EPI == 0) {
          outb[idx] = f2bf(v);
        } else if (EPI == 2) {
          v += bias[col] + resid[idx];
          outf[idx] = v;
        }
      }
    }
  }
}

// ---------------- V transpose: qkv[b*1024+n][2048+h*64+d] -> vt[(bh*64+d)*1024+n] ----------------
__global__ __launch_bounds__(256) void vtrans_kernel(const unsigned short* __restrict__ qkv,
                                                     unsigned short* __restrict__ vt) {
  __shared__ unsigned short T[64][66];   // [n_local][d], +2 pad
  const int nt = blockIdx.x, bh = blockIdx.y;
  const int b = bh >> 4, h = bh & 15;
  const unsigned short* src = qkv + (size_t)b * 1024 * 3072 + 2048 + h * 64;
  const int r = threadIdx.x >> 3, s = threadIdx.x & 7;
  ushort8 a0 = *reinterpret_cast<const ushort8*>(src + (size_t)(nt * 64 + r) * 3072 + s * 8);
  ushort8 a1 = *reinterpret_cast<const ushort8*>(src + (size_t)(nt * 64 + r + 32) * 3072 + s * 8);
  #pragma unroll
  for (int j = 0; j < 8; j++) {
    T[r][s * 8 + j]      = a0[j];
    T[r + 32][s * 8 + j] = a1[j];
  }
  __syncthreads();
  ushort8 o0, o1;
  #pragma unroll
  for (int j = 0; j < 8; j++) {
    o0[j] = T[s * 8 + j][r];
    o1[j] = T[s * 8 + j][r + 32];
  }
  unsigned short* dst = vt + (size_t)bh * 64 * 1024 + nt * 64 + s * 8;
  *reinterpret_cast<ushort8*>(dst + (size_t)r * 1024)        = o0;
  *reinterpret_cast<ushort8*>(dst + (size_t)(r + 32) * 1024) = o1;
}

// ---------------- Flash attention ----------------
// qkv: bf16 [B*N][3072] (q at col h*64, k at 1024+h*64); vt: bf16 [bh][64 d][1024 n]
// y:   bf16 [B*N][1024]
__global__ __launch_bounds__(256) void attn_kernel(const unsigned short* __restrict__ qkv,
                                                   const unsigned short* __restrict__ vt,
                                                   unsigned short* __restrict__ y) {
  __shared__ unsigned short Ks[2][64 * 64];  // [kv][d], slot-swizzled
  __shared__ unsigned short Vs[2][64 * 64];  // [d][kv], slot-swizzled
  __shared__ unsigned short Ps[4][16 * 64];  // per-wave [q][kv], swizzled

  const int tid = threadIdx.x;
  const int lane = tid & 63;
  const int w = tid >> 6;
  // XCD-aware bijective swizzle: 1024 blocks, 8 XCDs -> 16 qt of one bh stay on one XCD
  const int wg = (blockIdx.x & 7) * 128 + (blockIdx.x >> 3);
  const int bh = wg >> 4, qt = wg & 15;
  const int b = bh >> 4, h = bh & 15;
  const int fr = lane & 15, s0 = lane >> 4;
  const int fk = s0 * 8;
  const int sw = fr & 7;
  const size_t RS = 3072;

  const unsigned short* qbase = qkv + (size_t)b * 1024 * RS + h * 64;
  const unsigned short* kbase = qbase + 1024;
  const unsigned short* vbase = vt + (size_t)bh * 64 * 1024;

  // Q fragments (held for whole kernel)
  short8 aq[2];
  {
    const unsigned short* qrow = qbase + (size_t)(qt * 64 + w * 16 + fr) * RS;
    aq[0] = *reinterpret_cast<const short8*>(qrow + fk);
    aq[1] = *reinterpret_cast<const short8*>(qrow + 32 + fk);
  }

  float m_run[4], l_run[4];
  floatx4 accy[4];
  #pragma unroll
  for (int r = 0; r < 4; r++) { m_run[r] = -1e30f; l_run[r] = 0.f; }
  #pragma unroll
  for (int d = 0; d < 4; d++) accy[d] = (floatx4){0.f, 0.f, 0.f, 0.f};

  // staging geometry: row = tid>>3 (+32), 16B slot = tid&7; source slot inverse-swizzled
  const int krow0 = tid >> 3, kslot = tid & 7;
  const int gslot = (kslot ^ (krow0 & 7)) * 8;
  const unsigned short* kg0 = kbase + (size_t)krow0 * RS + gslot;
  const unsigned short* kg1 = kbase + (size_t)(krow0 + 32) * RS + gslot;
  const unsigned short* vg0 = vbase + (size_t)krow0 * 1024 + gslot;
  const unsigned short* vg1 = vbase + (size_t)(krow0 + 32) * 1024 + gslot;

  #define STAGE(t, buf)                                          \
    do {                                                         \
      const size_t ko = (size_t)(t) * 64 * RS;                   \
      const size_t vo = (size_t)(t) * 64;                        \
      gload_lds16(kg0 + ko, &Ks[buf][tid * 8]);                  \
      gload_lds16(kg1 + ko, &Ks[buf][(256 + tid) * 8]);          \
      gload_lds16(vg0 + vo, &Vs[buf][tid * 8]);                  \
      gload_lds16(vg1 + vo, &Vs[buf][(256 + tid) * 8]);          \
    } while (0)

  STAGE(0, 0);
  int cur = 0;

  for (int kt = 0; kt < 16; ++kt) {
    if (kt < 15) {
      STAGE(kt + 1, cur ^ 1);
      asm volatile("s_waitcnt vmcnt(4)" ::: "memory");
    } else {
      asm volatile("s_waitcnt vmcnt(0)" ::: "memory");
    }
    __builtin_amdgcn_s_barrier();

    const unsigned short* Kt = Ks[cur];
    const unsigned short* Vc = Vs[cur];

    // S = scale * Q K^T (16 q-rows x 64 kv)
    floatx4 sfr[4];
    #pragma unroll
    for (int f = 0; f < 4; ++f) {
      floatx4 s = (floatx4){0.f, 0.f, 0.f, 0.f};
      const unsigned short* krow = Kt + (f * 16 + fr) * 64;
      short8 kb0 = *reinterpret_cast<const short8*>(krow + (((s0)     ^ sw) << 3));
      short8 kb1 = *reinterpret_cast<const short8*>(krow + (((s0 + 4) ^ sw) << 3));
      s = __builtin_amdgcn_mfma_f32_16x16x32_bf16(aq[0], kb0, s, 0, 0, 0);
      s = __builtin_amdgcn_mfma_f32_16x16x32_bf16(aq[1], kb1, s, 0, 0, 0);
      sfr[f] = s * 0.125f;
    }

    // online softmax (rows live on 16-lane groups)
    #pragma unroll
    for (int r = 0; r < 4; r++) {
      float mv = fmaxf(fmaxf(sfr[0][r], sfr[1][r]), fmaxf(sfr[2][r], sfr[3][r]));
      #pragma unroll
      for (int m = 1; m < 16; m <<= 1) mv = fmaxf(mv, __shfl_xor(mv, m));
      const float mn = fmaxf(m_run[r], mv);
      const float alpha = __expf(m_run[r] - mn);
      m_run[r] = mn;
      const int q = s0 * 4 + r;
      const int qx = (q & 7) << 3;
      float ps = 0.f;
      #pragma unroll
      for (int f = 0; f < 4; f++) {
        float p = __expf(sfr[f][r] - mn);
        ps += p;
        Ps[w][q * 64 + ((f * 16 + fr) ^ qx)] = f2bf(p);
      }
      #pragma unroll
      for (int m = 1; m < 16; m <<= 1) ps += __shfl_xor(ps, m);
      l_run[r] = l_run[r] * alpha + ps;
      #pragma unroll
      for (int d = 0; d < 4; d++) accy[d][r] *= alpha;
    }

    // Y += P V   (A = P rows q, B = V^T rows d, contract over kv)
    #pragma unroll
    for (int ks = 0; ks < 2; ++ks) {
      const int sA = ((ks * 4 + s0) ^ sw) << 3;
      short8 ap = *reinterpret_cast<const short8*>(&Ps[w][fr * 64 + sA]);
      #pragma unroll
      for (int j = 0; j < 4; ++j) {
        short8 vb = *reinterpret_cast<const short8*>(Vc + (j * 16 + fr) * 64 + sA);
        accy[j] = __builtin_amdgcn_mfma_f32_16x16x32_bf16(ap, vb, accy[j], 0, 0, 0);
      }
    }
    __builtin_amdgcn_s_barrier();
    cur ^= 1;
  }
  #undef STAGE

  // write y (bf16) into [B*N][1024] at col h*64
  #pragma unroll
  for (int r = 0; r < 4; r++) {
    const float inv = 1.0f / l_run[r];
    const size_t grow =
        (size_t)(b * 1024 + qt * 64 + w * 16 + s0 * 4 + r) * 1024 + h * 64;
    #pragma unroll
    for (int d = 0; d < 4; ++d)
      y[grow + d * 16 + fr] = f2bf(accy[d][r] * inv);
  }
}

// ---------------- launcher ----------------
extern "C" void kernel_launch(void* const* d_in, const int* in_sizes, int n_in,
                              void* d_out, int out_size, void* d_ws, size_t ws_size,
                              hipStream_t stream) {
  const float* x      = (const float*)d_in[0];
  const float* qkv_w  = (const float*)d_in[1];
  const float* proj_w = (const float*)d_in[2];
  const float* proj_b = (const float*)d_in[3];
  const float* ln1_w  = (const float*)d_in[4];
  const float* ln1_b  = (const float*)d_in[5];
  const float* fc1_w  = (const float*)d_in[6];
  const float* fc1_b  = (const float*)d_in[7];
  const float* fc2_w  = (const float*)d_in[8];
  const float* fc2_b  = (const float*)d_in[9];
  const float* ln2_w  = (const float*)d_in[10];
  const float* ln2_b  = (const float*)d_in[11];
  float* out = (float*)d_out;

  char* ws = (char*)d_ws;
  unsigned short* qkvw16  = (unsigned short*)(ws + 0);          //  6.0 MB
  unsigned short* projw16 = (unsigned short*)(ws + 6291456);    //  2.0 MB
  unsigned short* fc1w16  = (unsigned short*)(ws + 8388608);    //  8.0 MB
  unsigned short* fc2w16  = (unsigned short*)(ws + 16777216);   //  8.0 MB
  float*          x1      = (float*)(ws + 25165824);            // 16.0 MB f32 (after attn)
  unsigned short* vt      = (unsigned short*)(ws + 25165824);   //  8.0 MB (dead before x1 written)
  unsigned short* xn      = (unsigned short*)(ws + 41943040);   //  8.0 MB (xn1 / y / xn2)
  unsigned short* big     = (unsigned short*)(ws + 50331648);   // 32.0 MB (qkvout / h)

  // weights -> bf16
  cvt_kernel<<<3072, 256, 0, stream>>>(qkv_w,  qkvw16, 786432);
  cvt_kernel<<<1024, 256, 0, stream>>>(proj_w, projw16, 262144);
  cvt_kernel<<<4096, 256, 0, stream>>>(fc1_w,  fc1w16, 1048576);
  cvt_kernel<<<4096, 256, 0, stream>>>(fc2_w,  fc2w16, 1048576);

  // LN1: x -> xn (bf16)
  ln_kernel<<<4096, 256, 0, stream>>>(x, ln1_w, ln1_b, xn);
  // qkv = xn * qkv_w^T  -> big (bf16 [4096][3072]); 16x12 = 192 blocks
  gemm256<0><<<192, 512, 0, stream>>>(xn, qkvw16, big, nullptr, 1024, 3072, 12);
  // V^T per head -> vt
  vtrans_kernel<<<dim3(16, 64), 256, 0, stream>>>(big, vt);
  // attention: big + vt -> xn (y, bf16 [4096][1024])
  attn_kernel<<<1024, 256, 0, stream>>>(big, vt, xn);
  // x1 = y * proj_w^T + proj_b + x  (f32); 32x8 = 256 blocks
  gemm128w8<2><<<256, 512, 0, stream>>>(xn, projw16, nullptr, x1, proj_b, x, 1024, 1024, 8);
  // LN2: x1 -> xn (bf16)
  ln_kernel<<<4096, 256, 0, stream>>>(x1, ln2_w, ln2_b, xn);
  // h = gelu(xn * fc1_w^T + fc1_b) -> big (bf16 [4096][4096]); 16x16 = 256 blocks
  gemm256<1><<<256, 512, 0, stream>>>(xn, fc1w16, big, fc1_b, 1024, 4096, 16);
  // out = h * fc2_w^T + fc2_b + x1  (f32); 32x8 = 256 blocks
  gemm128w8<2><<<256, 512, 0, stream>>>(big, fc2w16, nullptr, out, fc2_b, x1, 4096, 1024, 8);
}

// Round 6
// 252.670 us; speedup vs baseline: 1.4192x; 1.0543x over previous
//
#include <hip/hip_runtime.h>
#include <hip/hip_bf16.h>

typedef __attribute__((ext_vector_type(8))) short short8;
typedef __attribute__((ext_vector_type(8))) unsigned short ushort8;
typedef __attribute__((ext_vector_type(4))) float floatx4;

#define DEV static __device__ __forceinline__

DEV unsigned short f2bf(float f) {
  unsigned int u = __builtin_bit_cast(unsigned int, f);
  u += 0x7fff + ((u >> 16) & 1);   // round-to-nearest-even (no NaN inputs here)
  return (unsigned short)(u >> 16);
}
DEV float bf2f(unsigned short u) {
  return __builtin_bit_cast(float, (unsigned int)u << 16);
}

DEV void gload_lds16(const void* g, void* l) {
  __builtin_amdgcn_global_load_lds(
      (const __attribute__((address_space(1))) unsigned int*)g,
      (__attribute__((address_space(3))) unsigned int*)l, 16, 0, 0);
}

// ---------------- f32 -> bf16 converter: all 4 weights in one launch ----------------
__global__ __launch_bounds__(256) void cvt4_kernel(const float* __restrict__ w0,
                                                   const float* __restrict__ w1,
                                                   const float* __restrict__ w2,
                                                   const float* __restrict__ w3,
                                                   unsigned short* __restrict__ o0,
                                                   unsigned short* __restrict__ o1,
                                                   unsigned short* __restrict__ o2,
                                                   unsigned short* __restrict__ o3) {
  int i = blockIdx.x * 256 + threadIdx.x;   // grid covers 3145728 float4 groups
  const float* in; unsigned short* out; int j;
  if (i < 786432)       { in = w0; out = o0; j = i; }
  else if (i < 1048576) { in = w1; out = o1; j = i - 786432; }
  else if (i < 2097152) { in = w2; out = o2; j = i - 1048576; }
  else                  { in = w3; out = o3; j = i - 2097152; }
  float4 v = reinterpret_cast<const float4*>(in)[j];
  ushort4 o;
  o.x = f2bf(v.x); o.y = f2bf(v.y); o.z = f2bf(v.z); o.w = f2bf(v.w);
  reinterpret_cast<ushort4*>(out)[j] = o;
}

// ---------------- LayerNorm: f32 [rows][1024] -> bf16 ----------------
__global__ __launch_bounds__(256) void ln_kernel(const float* __restrict__ x,
                                                 const float* __restrict__ w,
                                                 const float* __restrict__ b,
                                                 unsigned short* __restrict__ out) {
  const int row = blockIdx.x;
  const float* xr = x + (size_t)row * 1024;
  float4 v = reinterpret_cast<const float4*>(xr)[threadIdx.x];
  float s  = v.x + v.y + v.z + v.w;
  float ss = v.x*v.x + v.y*v.y + v.z*v.z + v.w*v.w;
  #pragma unroll
  for (int off = 1; off < 64; off <<= 1) {
    s  += __shfl_xor(s, off);
    ss += __shfl_xor(ss, off);
  }
  __shared__ float red[8];
  const int wid = threadIdx.x >> 6, lane = threadIdx.x & 63;
  if (lane == 0) { red[wid] = s; red[4 + wid] = ss; }
  __syncthreads();
  s  = red[0] + red[1] + red[2] + red[3];
  ss = red[4] + red[5] + red[6] + red[7];
  const float mu  = s * (1.0f / 1024.0f);
  const float var = ss * (1.0f / 1024.0f) - mu * mu;
  const float rstd = rsqrtf(var + 1e-5f);
  float4 wv = reinterpret_cast<const float4*>(w)[threadIdx.x];
  float4 bv = reinterpret_cast<const float4*>(b)[threadIdx.x];
  ushort4 o;
  o.x = f2bf((v.x - mu) * rstd * wv.x + bv.x);
  o.y = f2bf((v.y - mu) * rstd * wv.y + bv.y);
  o.z = f2bf((v.z - mu) * rstd * wv.z + bv.z);
  o.w = f2bf((v.w - mu) * rstd * wv.w + bv.w);
  reinterpret_cast<ushort4*>(out)[(size_t)row * 256 + threadIdx.x] = o;
}

// ============ gemm256: C[M,N] = A[M,K] * B[N,K]^T, 256x256 tile, BK=64 ============
// 512 threads, 8 waves (2 M x 4 N). Double-buffered 128KB LDS, counted vmcnt(8),
// slot-XOR swizzle, 4-phase MFMA interleave + setprio.
// EPI 0: store bf16. EPI 1: +bias, tanh-GELU, store bf16.
template<int EPI>
__global__ __launch_bounds__(512, 2) void gemm256(const unsigned short* __restrict__ A,
                                                  const unsigned short* __restrict__ Bw,
                                                  unsigned short* __restrict__ outb,
                                                  const float* __restrict__ bias,
                                                  int K, int N, int NT) {
  __shared__ unsigned short As[2][256 * 64];
  __shared__ unsigned short Bs[2][256 * 64];
  const int tid = threadIdx.x, lane = tid & 63, wid = tid >> 6;
  const int wr = wid >> 2, wc = wid & 3;
  const int fr = lane & 15, s0 = lane >> 4;

  const int nwg = gridDim.x;
  const int qq = nwg >> 3, rr8 = nwg & 7, xcd = blockIdx.x & 7, lid = blockIdx.x >> 3;
  const int wg = (xcd < rr8 ? xcd * (qq + 1) : rr8 * (qq + 1) + (xcd - rr8) * qq) + lid;
  const int brow = (wg / NT) * 256, bcol = (wg % NT) * 256;

  const unsigned short* ag[4];
  const unsigned short* bg[4];
  #pragma unroll
  for (int L = 0; L < 4; L++) {
    const int idx = L * 512 + tid;
    const int row = idx >> 3;
    const int ss  = ((idx & 7) ^ (row & 7)) * 8;
    ag[L] = A  + (size_t)(brow + row) * K + ss;
    bg[L] = Bw + (size_t)(bcol + row) * K + ss;
  }
  const int ldst = tid * 8;

  #define STG256(kt, buf)                                                     \
    do {                                                                      \
      const int ko = (kt) * 64;                                               \
      gload_lds16(ag[0] + ko, &As[buf][ldst]);                                \
      gload_lds16(ag[1] + ko, &As[buf][4096 + ldst]);                         \
      gload_lds16(ag[2] + ko, &As[buf][8192 + ldst]);                         \
      gload_lds16(ag[3] + ko, &As[buf][12288 + ldst]);                        \
      gload_lds16(bg[0] + ko, &Bs[buf][ldst]);                                \
      gload_lds16(bg[1] + ko, &Bs[buf][4096 + ldst]);                         \
      gload_lds16(bg[2] + ko, &Bs[buf][8192 + ldst]);                         \
      gload_lds16(bg[3] + ko, &Bs[buf][12288 + ldst]);                        \
    } while (0)

  const int xs = fr & 7;
  const int aoff = (wr * 128 + fr) * 64;
  const int boff = (wc * 64 + fr) * 64;
  const int sl0 = ((0 + s0) ^ xs) * 8;
  const int sl1 = ((4 + s0) ^ xs) * 8;

  floatx4 acc[8][4];
  #pragma unroll
  for (int m = 0; m < 8; m++)
    #pragma unroll
    for (int n = 0; n < 4; n++) acc[m][n] = (floatx4){0.f, 0.f, 0.f, 0.f};

  const int NTK = K >> 6;
  STG256(0, 0);

  for (int kt = 0; kt < NTK; ++kt) {
    const int cur = kt & 1;
    if (kt + 1 < NTK) {
      STG256(kt + 1, cur ^ 1);
      asm volatile("s_waitcnt vmcnt(8)" ::: "memory");
    } else {
      asm volatile("s_waitcnt vmcnt(0)" ::: "memory");
    }
    __builtin_amdgcn_s_barrier();

    const unsigned short* Ac = As[cur];
    const unsigned short* Bc = Bs[cur];
    short8 a0[4][2], a1[4][2], b0[2][2], b1[2][2];

    #pragma unroll
    for (int m = 0; m < 4; m++) {
      a0[m][0] = *reinterpret_cast<const short8*>(Ac + aoff + m * 1024 + sl0);
      a0[m][1] = *reinterpret_cast<const short8*>(Ac + aoff + m * 1024 + sl1);
    }
    #pragma unroll
    for (int n = 0; n < 2; n++) {
      b0[n][0] = *reinterpret_cast<const short8*>(Bc + boff + n * 1024 + sl0);
      b0[n][1] = *reinterpret_cast<const short8*>(Bc + boff + n * 1024 + sl1);
    }
    __builtin_amdgcn_s_barrier();
    __builtin_amdgcn_s_setprio(1);
    #pragma unroll
    for (int m = 0; m < 4; m++)
      #pragma unroll
      for (int n = 0; n < 2; n++) {
        acc[m][n] = __builtin_amdgcn_mfma_f32_16x16x32_bf16(a0[m][0], b0[n][0], acc[m][n], 0, 0, 0);
        acc[m][n] = __builtin_amdgcn_mfma_f32_16x16x32_bf16(a0[m][1], b0[n][1], acc[m][n], 0, 0, 0);
      }
    __builtin_amdgcn_s_setprio(0);
    __builtin_amdgcn_s_barrier();

    #pragma unroll
    for (int n = 0; n < 2; n++) {
      b1[n][0] = *reinterpret_cast<const short8*>(Bc + boff + (n + 2) * 1024 + sl0);
      b1[n][1] = *reinterpret_cast<const short8*>(Bc + boff + (n + 2) * 1024 + sl1);
    }
    __builtin_amdgcn_s_barrier();
    __builtin_amdgcn_s_setprio(1);
    #pragma unroll
    for (int m = 0; m < 4; m++)
      #pragma unroll
      for (int n = 0; n < 2; n++) {
        acc[m][n + 2] = __builtin_amdgcn_mfma_f32_16x16x32_bf16(a0[m][0], b1[n][0], acc[m][n + 2], 0, 0, 0);
        acc[m][n + 2] = __builtin_amdgcn_mfma_f32_16x16x32_bf16(a0[m][1], b1[n][1], acc[m][n + 2], 0, 0, 0);
      }
    __builtin_amdgcn_s_setprio(0);
    __builtin_amdgcn_s_barrier();

    #pragma unroll
    for (int m = 0; m < 4; m++) {
      a1[m][0] = *reinterpret_cast<const short8*>(Ac + aoff + (m + 4) * 1024 + sl0);
      a1[m][1] = *reinterpret_cast<const short8*>(Ac + aoff + (m + 4) * 1024 + sl1);
    }
    __builtin_amdgcn_s_barrier();
    __builtin_amdgcn_s_setprio(1);
    #pragma unroll
    for (int m = 0; m < 4; m++)
      #pragma unroll
      for (int n = 0; n < 2; n++) {
        acc[m + 4][n] = __builtin_amdgcn_mfma_f32_16x16x32_bf16(a1[m][0], b0[n][0], acc[m + 4][n], 0, 0, 0);
        acc[m + 4][n] = __builtin_amdgcn_mfma_f32_16x16x32_bf16(a1[m][1], b0[n][1], acc[m + 4][n], 0, 0, 0);
      }
    __builtin_amdgcn_s_setprio(0);
    __builtin_amdgcn_s_barrier();

    __builtin_amdgcn_s_setprio(1);
    #pragma unroll
    for (int m = 0; m < 4; m++)
      #pragma unroll
      for (int n = 0; n < 2; n++) {
        acc[m + 4][n + 2] = __builtin_amdgcn_mfma_f32_16x16x32_bf16(a1[m][0], b1[n][0], acc[m + 4][n + 2], 0, 0, 0);
        acc[m + 4][n + 2] = __builtin_amdgcn_mfma_f32_16x16x32_bf16(a1[m][1], b1[n][1], acc[m + 4][n + 2], 0, 0, 0);
      }
    __builtin_amdgcn_s_setprio(0);
    __builtin_amdgcn_s_barrier();
  }
  #undef STG256

  #pragma unroll
  for (int m = 0; m < 8; m++) {
    #pragma unroll
    for (int n = 0; n < 4; n++) {
      const int col = bcol + wc * 64 + n * 16 + fr;
      #pragma unroll
      for (int r = 0; r < 4; r++) {
        const size_t idx = (size_t)(brow + wr * 128 + m * 16 + s0 * 4 + r) * N + col;
        float v = acc[m][n][r];
        if (EPI == 1) {
          v += bias[col];
          const float u = v * 0.7978845608f * (1.0f + 0.044715f * v * v);
          const float e = __expf(2.0f * u);
          v = v * (e / (e + 1.0f));
        }
        outb[idx] = f2bf(v);
      }
    }
  }
}

// ======== gemm128sk: split-K 128x128 tile, BK=32, 512 thr, 4-buf ring depth-3 ========
// R5 post-mortem: 96KB LDS forced 1 block/CU; K-step stayed ~2500cy (latency exposed).
// This version: 64KB LDS (BK=32 x 4 bufs) -> 2 blocks/CU = 16 waves/CU; grid doubled
// via split-K (kslice = wg/ntiles). Partials stored bf16 at outb + kslice*MN.
// Counted vmcnt: 2 loads/thread/tile, 3 tiles in flight -> 6 -> 4 -> 2 -> 0.
__global__ __launch_bounds__(512) void gemm128sk(const unsigned short* __restrict__ A,
                                                 const unsigned short* __restrict__ Bw,
                                                 unsigned short* __restrict__ outb,
                                                 int K, int Ksl, int N, int NT, int ntiles) {
  __shared__ unsigned short As[4][128 * 32];
  __shared__ unsigned short Bs[4][128 * 32];
  const int tid = threadIdx.x, lane = tid & 63, wid = tid >> 6;
  const int wrow = (wid >> 2) * 64, wcol = (wid & 3) * 32;
  const int fr = lane & 15, s0 = lane >> 4;

  // T1 bijective XCD swizzle over the whole (tile, kslice) grid
  const int nwg = gridDim.x;
  const int qq = nwg >> 3, rr8 = nwg & 7, xcd = blockIdx.x & 7, lid = blockIdx.x >> 3;
  const int wg = (xcd < rr8 ? xcd * (qq + 1) : rr8 * (qq + 1) + (xcd - rr8) * qq) + lid;
  const int kslice = wg / ntiles, t = wg % ntiles;
  const int brow = (t / NT) * 128, bcol = (t % NT) * 128;
  const int kofs = kslice * Ksl;

  // staging: 1 A + 1 B load/thread; row = tid>>2 (0..127), slot = tid&3
  // source slot inverse-swizzled with (row>>1)&3 (64B rows: parity feeds bit0 naturally)
  const int srow = tid >> 2;
  const int sslot = ((tid & 3) ^ ((srow >> 1) & 3)) * 8;
  const unsigned short* ag = A  + (size_t)(brow + srow) * K + kofs + sslot;
  const unsigned short* bg = Bw + (size_t)(bcol + srow) * K + kofs + sslot;
  const int ldst = tid * 8;

  #define STG(kt, buf)                              \
    do {                                            \
      const int ko = (kt) * 32;                     \
      gload_lds16(ag + ko, &As[buf][ldst]);         \
      gload_lds16(bg + ko, &Bs[buf][ldst]);         \
    } while (0)

  const int slr = (s0 ^ ((fr >> 1) & 3)) * 8;   // conflict-free read slot (R4-verified)

  floatx4 acc[4][2];
  #pragma unroll
  for (int i = 0; i < 4; i++)
    #pragma unroll
    for (int j = 0; j < 2; j++) acc[i][j] = (floatx4){0.f, 0.f, 0.f, 0.f};

  const int NTK = Ksl >> 5;
  STG(0, 0);
  STG(1, 1);
  STG(2, 2);

  for (int kt = 0; kt < NTK; ++kt) {
    const int cur = kt & 3;
    if (kt + 3 < NTK) {
      STG(kt + 3, (kt + 3) & 3);
      asm volatile("s_waitcnt vmcnt(6)" ::: "memory");   // tile kt landed; 3 ahead in flight
    } else if (kt + 2 < NTK) {
      asm volatile("s_waitcnt vmcnt(4)" ::: "memory");
    } else if (kt + 1 < NTK) {
      asm volatile("s_waitcnt vmcnt(2)" ::: "memory");
    } else {
      asm volatile("s_waitcnt vmcnt(0)" ::: "memory");
    }
    __builtin_amdgcn_s_barrier();

    short8 af[4], bf[2];
    #pragma unroll
    for (int i = 0; i < 4; i++)
      af[i] = *reinterpret_cast<const short8*>(&As[cur][(wrow + i * 16 + fr) * 32 + slr]);
    #pragma unroll
    for (int j = 0; j < 2; j++)
      bf[j] = *reinterpret_cast<const short8*>(&Bs[cur][(wcol + j * 16 + fr) * 32 + slr]);
    __builtin_amdgcn_s_setprio(1);
    #pragma unroll
    for (int i = 0; i < 4; i++)
      #pragma unroll
      for (int j = 0; j < 2; j++)
        acc[i][j] = __builtin_amdgcn_mfma_f32_16x16x32_bf16(af[i], bf[j], acc[i][j], 0, 0, 0);
    __builtin_amdgcn_s_setprio(0);
    __builtin_amdgcn_s_barrier();   // readers of 'cur' done before (kt+4)&3==cur restages
  }
  #undef STG

  unsigned short* po = outb + (size_t)kslice * ((size_t)ntiles * 16384);
  const int erow = brow + wrow + (s0 << 2);
  const int ecol = bcol + wcol + fr;
  #pragma unroll
  for (int i = 0; i < 4; i++)
    #pragma unroll
    for (int j = 0; j < 2; j++)
      #pragma unroll
      for (int r = 0; r < 4; r++)
        po[(size_t)(erow + i * 16 + r) * N + ecol + j * 16] = f2bf(acc[i][j][r]);
}

// ---- red_ln: x1 = p0+p1+proj_b+x ; xn = LN2(x1). One row per block. ----
__global__ __launch_bounds__(256) void red_ln(const unsigned short* __restrict__ p0,
                                              const unsigned short* __restrict__ p1,
                                              const float* __restrict__ x,
                                              const float* __restrict__ bias,
                                              const float* __restrict__ lw,
                                              const float* __restrict__ lb,
                                              float* __restrict__ x1,
                                              unsigned short* __restrict__ xn) {
  const int row = blockIdx.x, t = threadIdx.x;
  const size_t o4 = (size_t)row * 256 + t;
  ushort4 a = reinterpret_cast<const ushort4*>(p0)[o4];
  ushort4 c = reinterpret_cast<const ushort4*>(p1)[o4];
  float4 xv = reinterpret_cast<const float4*>(x)[o4];
  float4 bv = reinterpret_cast<const float4*>(bias)[t];
  float4 v;
  v.x = bf2f(a.x) + bf2f(c.x) + bv.x + xv.x;
  v.y = bf2f(a.y) + bf2f(c.y) + bv.y + xv.y;
  v.z = bf2f(a.z) + bf2f(c.z) + bv.z + xv.z;
  v.w = bf2f(a.w) + bf2f(c.w) + bv.w + xv.w;
  reinterpret_cast<float4*>(x1)[o4] = v;

  float s  = v.x + v.y + v.z + v.w;
  float ss = v.x*v.x + v.y*v.y + v.z*v.z + v.w*v.w;
  #pragma unroll
  for (int off = 1; off < 64; off <<= 1) {
    s  += __shfl_xor(s, off);
    ss += __shfl_xor(ss, off);
  }
  __shared__ float red[8];
  const int wid = t >> 6, lane = t & 63;
  if (lane == 0) { red[wid] = s; red[4 + wid] = ss; }
  __syncthreads();
  s  = red[0] + red[1] + red[2] + red[3];
  ss = red[4] + red[5] + red[6] + red[7];
  const float mu  = s * (1.0f / 1024.0f);
  const float var = ss * (1.0f / 1024.0f) - mu * mu;
  const float rstd = rsqrtf(var + 1e-5f);
  float4 wv = reinterpret_cast<const float4*>(lw)[t];
  float4 lv = reinterpret_cast<const float4*>(lb)[t];
  ushort4 o;
  o.x = f2bf((v.x - mu) * rstd * wv.x + lv.x);
  o.y = f2bf((v.y - mu) * rstd * wv.y + lv.y);
  o.z = f2bf((v.z - mu) * rstd * wv.z + lv.z);
  o.w = f2bf((v.w - mu) * rstd * wv.w + lv.w);
  reinterpret_cast<ushort4*>(xn)[o4] = o;
}

// ---- red_out: out = p0+p1+fc2_b+x1 (f32). One float4 per thread. ----
__global__ __launch_bounds__(256) void red_out(const unsigned short* __restrict__ p0,
                                               const unsigned short* __restrict__ p1,
                                               const float* __restrict__ x1,
                                               const float* __restrict__ bias,
                                               float* __restrict__ out) {
  const size_t i4 = (size_t)blockIdx.x * 256 + threadIdx.x;
  const int c4 = (int)(i4 & 255);
  ushort4 a = reinterpret_cast<const ushort4*>(p0)[i4];
  ushort4 c = reinterpret_cast<const ushort4*>(p1)[i4];
  float4 xv = reinterpret_cast<const float4*>(x1)[i4];
  float4 bv = reinterpret_cast<const float4*>(bias)[c4];
  float4 v;
  v.x = bf2f(a.x) + bf2f(c.x) + bv.x + xv.x;
  v.y = bf2f(a.y) + bf2f(c.y) + bv.y + xv.y;
  v.z = bf2f(a.z) + bf2f(c.z) + bv.z + xv.z;
  v.w = bf2f(a.w) + bf2f(c.w) + bv.w + xv.w;
  reinterpret_cast<float4*>(out)[i4] = v;
}

// ---------------- V transpose: qkv[b*1024+n][2048+h*64+d] -> vt[(bh*64+d)*1024+n] ----------------
__global__ __launch_bounds__(256) void vtrans_kernel(const unsigned short* __restrict__ qkv,
                                                     unsigned short* __restrict__ vt) {
  __shared__ unsigned short T[64][66];
  const int nt = blockIdx.x, bh = blockIdx.y;
  const int b = bh >> 4, h = bh & 15;
  const unsigned short* src = qkv + (size_t)b * 1024 * 3072 + 2048 + h * 64;
  const int r = threadIdx.x >> 3, s = threadIdx.x & 7;
  ushort8 a0 = *reinterpret_cast<const ushort8*>(src + (size_t)(nt * 64 + r) * 3072 + s * 8);
  ushort8 a1 = *reinterpret_cast<const ushort8*>(src + (size_t)(nt * 64 + r + 32) * 3072 + s * 8);
  #pragma unroll
  for (int j = 0; j < 8; j++) {
    T[r][s * 8 + j]      = a0[j];
    T[r + 32][s * 8 + j] = a1[j];
  }
  __syncthreads();
  ushort8 o0, o1;
  #pragma unroll
  for (int j = 0; j < 8; j++) {
    o0[j] = T[s * 8 + j][r];
    o1[j] = T[s * 8 + j][r + 32];
  }
  unsigned short* dst = vt + (size_t)bh * 64 * 1024 + nt * 64 + s * 8;
  *reinterpret_cast<ushort8*>(dst + (size_t)r * 1024)        = o0;
  *reinterpret_cast<ushort8*>(dst + (size_t)(r + 32) * 1024) = o1;
}

// ---------------- Flash attention ----------------
__global__ __launch_bounds__(256) void attn_kernel(const unsigned short* __restrict__ qkv,
                                                   const unsigned short* __restrict__ vt,
                                                   unsigned short* __restrict__ y) {
  __shared__ unsigned short Ks[2][64 * 64];
  __shared__ unsigned short Vs[2][64 * 64];
  __shared__ unsigned short Ps[4][16 * 64];

  const int tid = threadIdx.x;
  const int lane = tid & 63;
  const int w = tid >> 6;
  const int wg = (blockIdx.x & 7) * 128 + (blockIdx.x >> 3);
  const int bh = wg >> 4, qt = wg & 15;
  const int b = bh >> 4, h = bh & 15;
  const int fr = lane & 15, s0 = lane >> 4;
  const int fk = s0 * 8;
  const int sw = fr & 7;
  const size_t RS = 3072;

  const unsigned short* qbase = qkv + (size_t)b * 1024 * RS + h * 64;
  const unsigned short* kbase = qbase + 1024;
  const unsigned short* vbase = vt + (size_t)bh * 64 * 1024;

  short8 aq[2];
  {
    const unsigned short* qrow = qbase + (size_t)(qt * 64 + w * 16 + fr) * RS;
    aq[0] = *reinterpret_cast<const short8*>(qrow + fk);
    aq[1] = *reinterpret_cast<const short8*>(qrow + 32 + fk);
  }

  float m_run[4], l_run[4];
  floatx4 accy[4];
  #pragma unroll
  for (int r = 0; r < 4; r++) { m_run[r] = -1e30f; l_run[r] = 0.f; }
  #pragma unroll
  for (int d = 0; d < 4; d++) accy[d] = (floatx4){0.f, 0.f, 0.f, 0.f};

  const int krow0 = tid >> 3, kslot = tid & 7;
  const int gslot = (kslot ^ (krow0 & 7)) * 8;
  const unsigned short* kg0 = kbase + (size_t)krow0 * RS + gslot;
  const unsigned short* kg1 = kbase + (size_t)(krow0 + 32) * RS + gslot;
  const unsigned short* vg0 = vbase + (size_t)krow0 * 1024 + gslot;
  const unsigned short* vg1 = vbase + (size_t)(krow0 + 32) * 1024 + gslot;

  #define STAGE(t, buf)                                          \
    do {                                                         \
      const size_t ko = (size_t)(t) * 64 * RS;                   \
      const size_t vo = (size_t)(t) * 64;                        \
      gload_lds16(kg0 + ko, &Ks[buf][tid * 8]);                  \
      gload_lds16(kg1 + ko, &Ks[buf][(256 + tid) * 8]);          \
      gload_lds16(vg0 + vo, &Vs[buf][tid * 8]);                  \
      gload_lds16(vg1 + vo, &Vs[buf][(256 + tid) * 8]);          \
    } while (0)

  STAGE(0, 0);
  int cur = 0;

  for (int kt = 0; kt < 16; ++kt) {
    if (kt < 15) {
      STAGE(kt + 1, cur ^ 1);
      asm volatile("s_waitcnt vmcnt(4)" ::: "memory");
    } else {
      asm volatile("s_waitcnt vmcnt(0)" ::: "memory");
    }
    __builtin_amdgcn_s_barrier();

    const unsigned short* Kt = Ks[cur];
    const unsigned short* Vc = Vs[cur];

    floatx4 sfr[4];
    #pragma unroll
    for (int f = 0; f < 4; ++f) {
      floatx4 s = (floatx4){0.f, 0.f, 0.f, 0.f};
      const unsigned short* krow = Kt + (f * 16 + fr) * 64;
      short8 kb0 = *reinterpret_cast<const short8*>(krow + (((s0)     ^ sw) << 3));
      short8 kb1 = *reinterpret_cast<const short8*>(krow + (((s0 + 4) ^ sw) << 3));
      s = __builtin_amdgcn_mfma_f32_16x16x32_bf16(aq[0], kb0, s, 0, 0, 0);
      s = __builtin_amdgcn_mfma_f32_16x16x32_bf16(aq[1], kb1, s, 0, 0, 0);
      sfr[f] = s * 0.125f;
    }

    #pragma unroll
    for (int r = 0; r < 4; r++) {
      float mv = fmaxf(fmaxf(sfr[0][r], sfr[1][r]), fmaxf(sfr[2][r], sfr[3][r]));
      #pragma unroll
      for (int m = 1; m < 16; m <<= 1) mv = fmaxf(mv, __shfl_xor(mv, m));
      const float mn = fmaxf(m_run[r], mv);
      const float alpha = __expf(m_run[r] - mn);
      m_run[r] = mn;
      const int q = s0 * 4 + r;
      const int qx = (q & 7) << 3;
      float ps = 0.f;
      #pragma unroll
      for (int f = 0; f < 4; f++) {
        float p = __expf(sfr[f][r] - mn);
        ps += p;
        Ps[w][q * 64 + ((f * 16 + fr) ^ qx)] = f2bf(p);
      }
      #pragma unroll
      for (int m = 1; m < 16; m <<= 1) ps += __shfl_xor(ps, m);
      l_run[r] = l_run[r] * alpha + ps;
      #pragma unroll
      for (int d = 0; d < 4; d++) accy[d][r] *= alpha;
    }

    #pragma unroll
    for (int ks = 0; ks < 2; ++ks) {
      const int sA = ((ks * 4 + s0) ^ sw) << 3;
      short8 ap = *reinterpret_cast<const short8*>(&Ps[w][fr * 64 + sA]);
      #pragma unroll
      for (int j = 0; j < 4; ++j) {
        short8 vb = *reinterpret_cast<const short8*>(Vc + (j * 16 + fr) * 64 + sA);
        accy[j] = __builtin_amdgcn_mfma_f32_16x16x32_bf16(ap, vb, accy[j], 0, 0, 0);
      }
    }
    __builtin_amdgcn_s_barrier();
    cur ^= 1;
  }
  #undef STAGE

  #pragma unroll
  for (int r = 0; r < 4; r++) {
    const float inv = 1.0f / l_run[r];
    const size_t grow =
        (size_t)(b * 1024 + qt * 64 + w * 16 + s0 * 4 + r) * 1024 + h * 64;
    #pragma unroll
    for (int d = 0; d < 4; ++d)
      y[grow + d * 16 + fr] = f2bf(accy[d][r] * inv);
  }
}

// ---------------- launcher ----------------
extern "C" void kernel_launch(void* const* d_in, const int* in_sizes, int n_in,
                              void* d_out, int out_size, void* d_ws, size_t ws_size,
                              hipStream_t stream) {
  const float* x      = (const float*)d_in[0];
  const float* qkv_w  = (const float*)d_in[1];
  const float* proj_w = (const float*)d_in[2];
  const float* proj_b = (const float*)d_in[3];
  const float* ln1_w  = (const float*)d_in[4];
  const float* ln1_b  = (const float*)d_in[5];
  const float* fc1_w  = (const float*)d_in[6];
  const float* fc1_b  = (const float*)d_in[7];
  const float* fc2_w  = (const float*)d_in[8];
  const float* fc2_b  = (const float*)d_in[9];
  const float* ln2_w  = (const float*)d_in[10];
  const float* ln2_b  = (const float*)d_in[11];
  float* out = (float*)d_out;

  char* ws = (char*)d_ws;
  unsigned short* qkvw16  = (unsigned short*)(ws + 0);          //  6.0 MB
  unsigned short* projw16 = (unsigned short*)(ws + 6291456);    //  2.0 MB
  unsigned short* fc1w16  = (unsigned short*)(ws + 8388608);    //  8.0 MB
  unsigned short* fc2w16  = (unsigned short*)(ws + 16777216);   //  8.0 MB
  float*          x1      = (float*)(ws + 25165824);            // 16.0 MB f32 (after attn)
  unsigned short* vt      = (unsigned short*)(ws + 25165824);   //  8.0 MB (dead before x1 written)
  unsigned short* xn      = (unsigned short*)(ws + 41943040);   //  8.0 MB (xn1 / y / xn2)
  unsigned short* big     = (unsigned short*)(ws + 50331648);   // 32.0 MB (qkvout / proj-partials / h)
  unsigned short* pp      = big;                                // proj partials: 2 x 8 MB (qkv dead)
  unsigned short* fp      = (unsigned short*)(ws + 0);          // fc2 partials: 2 x 8 MB (weights dead)

  // weights -> bf16 (single launch)
  cvt4_kernel<<<12288, 256, 0, stream>>>(qkv_w, proj_w, fc1_w, fc2_w,
                                         qkvw16, projw16, fc1w16, fc2w16);

  // LN1: x -> xn (bf16)
  ln_kernel<<<4096, 256, 0, stream>>>(x, ln1_w, ln1_b, xn);
  // qkv = xn * qkv_w^T  -> big (bf16 [4096][3072]); 16x12 = 192 blocks
  gemm256<0><<<192, 512, 0, stream>>>(xn, qkvw16, big, nullptr, 1024, 3072, 12);
  // V^T per head -> vt
  vtrans_kernel<<<dim3(16, 64), 256, 0, stream>>>(big, vt);
  // attention: big + vt -> xn (y, bf16 [4096][1024])
  attn_kernel<<<1024, 256, 0, stream>>>(big, vt, xn);
  // proj (split-K=2): y * proj_w^T -> pp (2 x bf16 [4096][1024]); 256 tiles x 2 = 512 blocks
  gemm128sk<<<512, 512, 0, stream>>>(xn, projw16, pp, 1024, 512, 1024, 8, 256);
  // x1 = pp0+pp1+proj_b+x ; xn = LN2(x1)
  red_ln<<<4096, 256, 0, stream>>>(pp, pp + 4194304, x, proj_b, ln2_w, ln2_b, x1, xn);
  // h = gelu(xn * fc1_w^T + fc1_b) -> big (bf16 [4096][4096]); 16x16 = 256 blocks
  gemm256<1><<<256, 512, 0, stream>>>(xn, fc1w16, big, fc1_b, 1024, 4096, 16);
  // fc2 (split-K=2): h * fc2_w^T -> fp (2 x bf16 [4096][1024]); 512 blocks
  gemm128sk<<<512, 512, 0, stream>>>(big, fc2w16, fp, 4096, 2048, 1024, 8, 256);
  // out = fp0+fp1+fc2_b+x1
  red_out<<<4096, 256, 0, stream>>>(fp, fp + 4194304, x1, fc2_b, out);
}